// Round 1
// baseline (531.693 us; speedup 1.0000x reference)
//
#include <hip/hip_runtime.h>
#include <hip/hip_bf16.h>
#include <math.h>

#define B_ 2
#define L_ 2048
#define C_ 1024
#define H_ 16
#define D_ 64
#define K_ 64
#define S_ 33
#define M_ (B_*L_)

__device__ __forceinline__ float sigmoidf_(float v) { return 1.f / (1.f + __expf(-v)); }

// ---------------------------------------------------------------------------
// Tiled fp32 GEMM:  C[m][n] = dot(A[m][:], Bw[n][:])  (+ optional silu)
// A: MxKd row-major, Bw: NxKd row-major (we multiply by Bw^T).
// Tiles 128x128, BK=16, 256 threads, 8x8 per thread.
// M,N multiples of 128; Kd multiple of 16. LDS stride 132 floats = 528B
// (16B-aligned for float4 reads; 4*132=528, 528%32banks=16 -> 2-way store, free)
// ---------------------------------------------------------------------------
template<int SILU>
__global__ __launch_bounds__(256) void gemm_nt(
    const float* __restrict__ A, const float* __restrict__ Bw,
    float* __restrict__ Co, int M, int N, int Kd)
{
  __shared__ float As[16][132];
  __shared__ float Bs[16][132];
  int tid = threadIdx.x;
  int m0 = blockIdx.y * 128, n0 = blockIdx.x * 128;
  int tx = tid & 15, ty = tid >> 4;
  float acc[8][8] = {};
  const float4* Ag = (const float4*)A;
  const float4* Bg = (const float4*)Bw;
  int Kd4 = Kd >> 2;

  for (int k0 = 0; k0 < Kd; k0 += 16) {
    int kb = k0 >> 2;
#pragma unroll
    for (int q = 0; q < 2; q++) {
      int idx = tid + q * 256;      // 0..511
      int row = idx >> 2;           // 0..127
      int kg  = idx & 3;            // 0..3
      float4 av = Ag[(size_t)(m0 + row) * Kd4 + kb + kg];
      float4 bv = Bg[(size_t)(n0 + row) * Kd4 + kb + kg];
      As[kg*4+0][row] = av.x; As[kg*4+1][row] = av.y;
      As[kg*4+2][row] = av.z; As[kg*4+3][row] = av.w;
      Bs[kg*4+0][row] = bv.x; Bs[kg*4+1][row] = bv.y;
      Bs[kg*4+2][row] = bv.z; Bs[kg*4+3][row] = bv.w;
    }
    __syncthreads();
#pragma unroll
    for (int kk = 0; kk < 16; kk++) {
      float a[8], bb[8];
#pragma unroll
      for (int i = 0; i < 8; i++) a[i] = As[kk][ty*8 + i];
#pragma unroll
      for (int j = 0; j < 8; j++) bb[j] = Bs[kk][tx*8 + j];
#pragma unroll
      for (int i = 0; i < 8; i++)
#pragma unroll
        for (int j = 0; j < 8; j++)
          acc[i][j] += a[i] * bb[j];
    }
    __syncthreads();
  }

#pragma unroll
  for (int i = 0; i < 8; i++) {
    int mrow = m0 + ty*8 + i;
    float* crow = Co + (size_t)mrow * N + n0 + tx*8;
    float v[8];
#pragma unroll
    for (int j = 0; j < 8; j++) {
      float t = acc[i][j];
      v[j] = SILU ? (t * sigmoidf_(t)) : t;
    }
    *(float4*)(crow)     = make_float4(v[0], v[1], v[2], v[3]);
    *(float4*)(crow + 4) = make_float4(v[4], v[5], v[6], v[7]);
  }
}

// ---------------------------------------------------------------------------
// Per-token postprocess: wave dots (32) + exp dot (1) + rmsnorms + silu,
// and kern-row rmsnorm+silu applied in-place to ykern -> kernel_max.
// One block (256 threads) per token.
// ---------------------------------------------------------------------------
__global__ __launch_bounds__(256) void token_post(
    const float* __restrict__ x,
    const float* __restrict__ w_wave, const float* __restrict__ b_wave,
    const float* __restrict__ g_wave,
    const float* __restrict__ b_kern, const float* __restrict__ g_kern,
    const float* __restrict__ w_exp, const float* __restrict__ b_exp,
    const float* __restrict__ g_exp,
    float* __restrict__ ykern,                // in: raw proj; out: kernel_max
    float* __restrict__ freq, float* __restrict__ phase,
    float* __restrict__ expn)
{
  __shared__ float xs[C_];
  __shared__ float dots[S_];   // 32 wave + 1 exp
  __shared__ float red[8];
  int m = blockIdx.x;
  int tid = threadIdx.x;
  int lane = tid & 63, wid = tid >> 6;

  ((float4*)xs)[tid] = ((const float4*)(x + (size_t)m * C_))[tid];
  __syncthreads();

  // 33 dot products, one per wave-iteration
  for (int n = wid; n < 33; n += 4) {
    const float* wr = (n < 32) ? (w_wave + n * C_) : w_exp;
    float s = 0.f;
    for (int k = lane; k < C_; k += 64) s += xs[k] * wr[k];
    for (int o = 32; o; o >>= 1) s += __shfl_xor(s, o);
    if (lane == 0) dots[n] = s + ((n < 32) ? b_wave[n] : b_exp[0]);
  }
  __syncthreads();

  // rmsnorm(32) + silu on the wave segment
  if (tid < 64) {
    float v = (tid < 32) ? dots[tid] : 0.f;
    float ss = v * v;
    for (int o = 32; o; o >>= 1) ss += __shfl_xor(ss, o);
    float scale = rsqrtf(ss * (1.f / 32.f) + 1e-6f);
    if (tid < 32) {
      float nv = dots[tid] * scale * g_wave[tid];
      dots[tid] = nv * sigmoidf_(nv);
    }
  }
  __syncthreads();
  if (tid < 16) {
    freq[m * H_ + tid]  = sigmoidf_(dots[tid]) * 15.f + 1.f;
    phase[m * H_ + tid] = tanhf(dots[16 + tid]) * 16.f;
  }
  if (tid == 0) {
    float y = dots[32];
    float nv = y * rsqrtf(y * y + 1e-6f) * g_exp[0];
    expn[m] = sigmoidf_(nv) * 3.5f + 0.5f;
  }

  // kern rmsnorm + silu (1024 channels, in-place)
  float y[4];
  float ss = 0.f;
#pragma unroll
  for (int i = 0; i < 4; i++) {
    int c = tid + i * 256;
    y[i] = ykern[(size_t)m * C_ + c] + b_kern[c];
    ss += y[i] * y[i];
  }
  for (int o = 32; o; o >>= 1) ss += __shfl_xor(ss, o);
  if (lane == 0) red[wid] = ss;
  __syncthreads();
  if (tid == 0) red[4] = rsqrtf((red[0]+red[1]+red[2]+red[3]) * (1.f/1024.f) + 1e-6f);
  __syncthreads();
  float scale = red[4];
#pragma unroll
  for (int i = 0; i < 4; i++) {
    int c = tid + i * 256;
    float nv = y[i] * scale * g_kern[c];
    ykern[(size_t)m * C_ + c] = nv * sigmoidf_(nv);
  }
}

// ---------------------------------------------------------------------------
// Sampler: one block (1024 thr) per token. wave = head, lane = d.
// hidden[b,l,h,d] = sum_s kern(s) * (vf*(1-frac) + vc*frac)
// ---------------------------------------------------------------------------
__global__ __launch_bounds__(1024) void sampler(
    const float* __restrict__ x,
    const float* __restrict__ km_g,
    const float* __restrict__ freq, const float* __restrict__ phase,
    const float* __restrict__ expn,
    float* __restrict__ hidden)
{
  __shared__ float km[C_];
  int m = blockIdx.x;
  int tid = threadIdx.x;
  int h = tid >> 6, d = tid & 63;
  km[tid] = km_g[(size_t)m * C_ + tid];
  __syncthreads();
  int b = m >> 11, l = m & (L_ - 1);
  float f  = freq[m * H_ + h];
  float ph = phase[m * H_ + h];
  float e  = expn[m];
  const float* xb = x + (size_t)b * L_ * C_;
  float acc = 0.f;

  for (int s = 0; s < S_; s++) {
    float off = (float)(s - 16);
    float rel = off * f;
    float posv = (float)l + rel + ph;
    if (!(posv >= 0.f && posv < 2048.f)) continue;   // wave-uniform
    float pc = fminf(fmaxf(posv, 0.f), 2046.999f);
    int fl = (int)pc;                 // pc >= 0 so trunc == floor; fl <= 2046
    float frac = pc - (float)fl;
    float ar = fabsf(rel);
    float idx_f = fminf(ar * (1.f / 256.f), 1.f) * 63.f;
    int i0 = (int)idx_f; if (i0 > 62) i0 = 62;
    float wc = idx_f - (float)i0;
    float k0 = km[(h << 6) + i0];
    float k1 = km[(h << 6) + i0 + 1];
    float powv = __expf(-e * __logf(1.f + ar * (1.f / 2048.f)));
    float kern = (k0 * (1.f - wc) + k1 * wc) * powv;
    const float* pf = xb + (size_t)fl * C_ + (h << 6) + d;
    float vf = pf[0];
    float vc = pf[C_];                // cl = fl+1 (fl <= 2046)
    acc += kern * (vf * (1.f - frac) + vc * frac);
  }
  hidden[(size_t)m * C_ + tid] = acc;
}

// ---------------------------------------------------------------------------
extern "C" void kernel_launch(void* const* d_in, const int* in_sizes, int n_in,
                              void* d_out, int out_size, void* d_ws, size_t ws_size,
                              hipStream_t stream) {
  const float* x      = (const float*)d_in[0];
  const float* w_wave = (const float*)d_in[1];
  const float* b_wave = (const float*)d_in[2];
  const float* g_wave = (const float*)d_in[3];
  const float* w_kern = (const float*)d_in[4];
  const float* b_kern = (const float*)d_in[5];
  const float* g_kern = (const float*)d_in[6];
  const float* w_exp  = (const float*)d_in[7];
  const float* b_exp  = (const float*)d_in[8];
  const float* g_exp  = (const float*)d_in[9];
  const float* w_out  = (const float*)d_in[10];
  float* out = (float*)d_out;

  float* ws = (float*)d_ws;
  float* ykern  = ws;                          // M*C (becomes kernel_max)
  float* hidden = ykern + (size_t)M_ * C_;     // M*C
  float* freqb  = hidden + (size_t)M_ * C_;    // M*H
  float* phaseb = freqb + (size_t)M_ * H_;     // M*H
  float* expnb  = phaseb + (size_t)M_ * H_;    // M

  dim3 gg(C_ / 128, M_ / 128);   // (8, 32)
  gemm_nt<0><<<gg, 256, 0, stream>>>(x, w_kern, ykern, M_, C_, C_);
  token_post<<<M_, 256, 0, stream>>>(x, w_wave, b_wave, g_wave, b_kern, g_kern,
                                     w_exp, b_exp, g_exp, ykern, freqb, phaseb, expnb);
  sampler<<<M_, 1024, 0, stream>>>(x, ykern, freqb, phaseb, expnb, hidden);
  gemm_nt<1><<<gg, 256, 0, stream>>>(hidden, w_out, out, M_, C_, C_);
}

// Round 2
// 276.392 us; speedup vs baseline: 1.9237x; 1.9237x over previous
//
#include <hip/hip_runtime.h>
#include <hip/hip_bf16.h>
#include <math.h>

#define B_ 2
#define L_ 2048
#define C_ 1024
#define H_ 16
#define D_ 64
#define K_ 64
#define S_ 33
#define M_ (B_*L_)

typedef _Float16 half8 __attribute__((ext_vector_type(8)));
typedef float f32x4 __attribute__((ext_vector_type(4)));

__device__ __forceinline__ float sigmoidf_(float v) { return 1.f / (1.f + __expf(-v)); }

// ---------------------------------------------------------------------------
// fp32 -> fp16 conversion, 8 elems/thread (16B stores)
// ---------------------------------------------------------------------------
__global__ __launch_bounds__(256) void f2h(const float* __restrict__ in,
                                           _Float16* __restrict__ out, int n8) {
  int i = blockIdx.x * 256 + threadIdx.x;
  if (i >= n8) return;
  const float4* p = (const float4*)in + (size_t)i * 2;
  float4 a = p[0], b = p[1];
  union { _Float16 h[8]; uint4 u; } v;
  v.h[0] = (_Float16)a.x; v.h[1] = (_Float16)a.y;
  v.h[2] = (_Float16)a.z; v.h[3] = (_Float16)a.w;
  v.h[4] = (_Float16)b.x; v.h[5] = (_Float16)b.y;
  v.h[6] = (_Float16)b.z; v.h[7] = (_Float16)b.w;
  ((uint4*)out)[i] = v.u;
}

// ---------------------------------------------------------------------------
// FP16-MFMA GEMM (m97 structure): C[m][n] = dot(A[m][:], Bw[n][:]) (+silu)
// A: MxKd, Bw: NxKd row-major fp16. 128x128 tile, BK=32, 256 thr (4 waves,
// 2x2 of 64x64). global_load_lds width 16; linear LDS [row][32] fp16.
// ---------------------------------------------------------------------------
template<int SILU>
__global__ __launch_bounds__(256) void gemm_h(
    const _Float16* __restrict__ A, const _Float16* __restrict__ Bw,
    float* __restrict__ Co, int M, int N, int Kd)
{
  __shared__ __align__(16) _Float16 As[128 * 32];
  __shared__ __align__(16) _Float16 Bs[128 * 32];
  int tid = threadIdx.x;
  int m0 = blockIdx.y * 128, n0 = blockIdx.x * 128;
  int lane = tid & 63;
  int wid = tid >> 6, wm = wid >> 1, wn = wid & 1;

  f32x4 acc[4][4];
#pragma unroll
  for (int i = 0; i < 4; i++)
#pragma unroll
    for (int j = 0; j < 4; j++)
      acc[i][j] = (f32x4){0.f, 0.f, 0.f, 0.f};

  for (int k0 = 0; k0 < Kd; k0 += 32) {
#pragma unroll
    for (int q = 0; q < 2; q++) {
      int idx = tid + q * 256;          // 0..511
      int row = idx >> 2, seg = idx & 3;
      const _Float16* ga = A  + (size_t)(m0 + row) * Kd + k0 + seg * 8;
      const _Float16* gb = Bw + (size_t)(n0 + row) * Kd + k0 + seg * 8;
      __builtin_amdgcn_global_load_lds(
          (const __attribute__((address_space(1))) unsigned int*)ga,
          (__attribute__((address_space(3))) unsigned int*)&As[idx * 8], 16, 0, 0);
      __builtin_amdgcn_global_load_lds(
          (const __attribute__((address_space(1))) unsigned int*)gb,
          (__attribute__((address_space(3))) unsigned int*)&Bs[idx * 8], 16, 0, 0);
    }
    __syncthreads();

    half8 aF[4], bF[4];
#pragma unroll
    for (int i = 0; i < 4; i++)
      aF[i] = *(const half8*)&As[(wm * 64 + i * 16 + (lane & 15)) * 32 + (lane >> 4) * 8];
#pragma unroll
    for (int j = 0; j < 4; j++)
      bF[j] = *(const half8*)&Bs[(wn * 64 + j * 16 + (lane & 15)) * 32 + (lane >> 4) * 8];
#pragma unroll
    for (int i = 0; i < 4; i++)
#pragma unroll
      for (int j = 0; j < 4; j++)
        acc[i][j] = __builtin_amdgcn_mfma_f32_16x16x32_f16(aF[i], bF[j], acc[i][j], 0, 0, 0);
    __syncthreads();
  }

  // C/D: col = lane&15, row = (lane>>4)*4 + reg  [m89/m91 verified]
#pragma unroll
  for (int i = 0; i < 4; i++)
#pragma unroll
    for (int j = 0; j < 4; j++) {
      int col = n0 + wn * 64 + j * 16 + (lane & 15);
#pragma unroll
      for (int r = 0; r < 4; r++) {
        int row = m0 + wm * 64 + i * 16 + (lane >> 4) * 4 + r;
        float t = acc[i][j][r];
        if (SILU) t = t * sigmoidf_(t);
        Co[(size_t)row * N + col] = t;
      }
    }
}

// ---------------------------------------------------------------------------
// Per-token postprocess (fp32 throughout — position params are precision-
// critical): wave dots (32) + exp dot + rmsnorms + silu; kern rmsnorm+silu
// in-place on ykern. One 256-thread block per token.
// ---------------------------------------------------------------------------
__global__ __launch_bounds__(256) void token_post(
    const float* __restrict__ x,
    const float* __restrict__ w_wave, const float* __restrict__ b_wave,
    const float* __restrict__ g_wave,
    const float* __restrict__ b_kern, const float* __restrict__ g_kern,
    const float* __restrict__ w_exp, const float* __restrict__ b_exp,
    const float* __restrict__ g_exp,
    float* __restrict__ ykern,
    float* __restrict__ freq, float* __restrict__ phase,
    float* __restrict__ expn)
{
  __shared__ float xs[C_];
  __shared__ float dots[S_];
  __shared__ float red[8];
  int m = blockIdx.x;
  int tid = threadIdx.x;
  int lane = tid & 63, wid = tid >> 6;

  ((float4*)xs)[tid] = ((const float4*)(x + (size_t)m * C_))[tid];
  __syncthreads();

  for (int n = wid; n < 33; n += 4) {
    const float* wr = (n < 32) ? (w_wave + n * C_) : w_exp;
    float s = 0.f;
    for (int k = lane; k < 256; k += 64) {       // float4 units
      float4 xv = ((const float4*)xs)[k];
      float4 wv = ((const float4*)wr)[k];
      s += xv.x * wv.x + xv.y * wv.y + xv.z * wv.z + xv.w * wv.w;
    }
    for (int o = 32; o; o >>= 1) s += __shfl_xor(s, o);
    if (lane == 0) dots[n] = s + ((n < 32) ? b_wave[n] : b_exp[0]);
  }
  __syncthreads();

  if (tid < 64) {
    float v = (tid < 32) ? dots[tid] : 0.f;
    float ss = v * v;
    for (int o = 32; o; o >>= 1) ss += __shfl_xor(ss, o);
    float scale = rsqrtf(ss * (1.f / 32.f) + 1e-6f);
    if (tid < 32) {
      float nv = dots[tid] * scale * g_wave[tid];
      dots[tid] = nv * sigmoidf_(nv);
    }
  }
  __syncthreads();
  if (tid < 16) {
    freq[m * H_ + tid]  = sigmoidf_(dots[tid]) * 15.f + 1.f;
    phase[m * H_ + tid] = tanhf(dots[16 + tid]) * 16.f;
  }
  if (tid == 0) {
    float y = dots[32];
    float nv = y * rsqrtf(y * y + 1e-6f) * g_exp[0];
    expn[m] = sigmoidf_(nv) * 3.5f + 0.5f;
  }

  float y[4];
  float ss = 0.f;
#pragma unroll
  for (int i = 0; i < 4; i++) {
    int c = tid + i * 256;
    y[i] = ykern[(size_t)m * C_ + c] + b_kern[c];
    ss += y[i] * y[i];
  }
  for (int o = 32; o; o >>= 1) ss += __shfl_xor(ss, o);
  if (lane == 0) red[wid] = ss;
  __syncthreads();
  if (tid == 0) red[4] = rsqrtf((red[0] + red[1] + red[2] + red[3]) * (1.f / 1024.f) + 1e-6f);
  __syncthreads();
  float scale = red[4];
#pragma unroll
  for (int i = 0; i < 4; i++) {
    int c = tid + i * 256;
    float nv = y[i] * scale * g_kern[c];
    ykern[(size_t)m * C_ + c] = nv * sigmoidf_(nv);
  }
}

// ---------------------------------------------------------------------------
// Sampler v2: one 1024-thr block/token. Phase 1: 528 threads compute
// per-(h,s) kern weight / frac / floor-index into LDS (all transcendentals
// here, once instead of 64x). Phase 2: thread (h,d) gathers+lerps+accums.
// Writes hidden as fp16 (consumed by gemm_h).
// ---------------------------------------------------------------------------
__global__ __launch_bounds__(1024) void sampler(
    const float* __restrict__ x, const float* __restrict__ km_g,
    const float* __restrict__ freq, const float* __restrict__ phase,
    const float* __restrict__ expn, _Float16* __restrict__ hidden)
{
  __shared__ float kw[H_][S_];
  __shared__ float fr[H_][S_];
  __shared__ int   fli[H_][S_];
  int m = blockIdx.x, tid = threadIdx.x;
  int b = m >> 11, l = m & (L_ - 1);

  if (tid < H_ * S_) {
    int h = tid / S_, s = tid - h * S_;
    float f  = freq[m * H_ + h];
    float ph = phase[m * H_ + h];
    float e  = expn[m];
    float rel = (float)(s - 16) * f;
    float posv = (float)l + rel + ph;
    float kern = 0.f, frac = 0.f;
    int fl = 0;
    if (posv >= 0.f && posv < 2048.f) {
      float pc = fminf(posv, 2046.999f);
      fl = (int)pc;                       // pc>=0 -> trunc==floor, fl<=2046
      frac = pc - (float)fl;
      float ar = fabsf(rel);
      float idx_f = fminf(ar * (1.f / 256.f), 1.f) * 63.f;
      int i0 = (int)idx_f; if (i0 > 62) i0 = 62;
      float wc = idx_f - (float)i0;
      float k0 = km_g[(size_t)m * C_ + (h << 6) + i0];
      float k1 = km_g[(size_t)m * C_ + (h << 6) + i0 + 1];
      float powv = __expf(-e * __logf(1.f + ar * (1.f / 2048.f)));
      kern = (k0 * (1.f - wc) + k1 * wc) * powv;
    }
    kw[h][s] = kern; fr[h][s] = frac; fli[h][s] = fl;
  }
  __syncthreads();

  int h = tid >> 6, d = tid & 63;
  const float* xb = x + (size_t)b * L_ * C_ + (h << 6) + d;
  float acc = 0.f;
  for (int s = 0; s < S_; s++) {
    float kern = kw[h][s];                 // LDS broadcast (uniform per wave)
    if (kern == 0.f) continue;             // wave-uniform branch
    int fl = fli[h][s];
    float frac = fr[h][s];
    const float* pf = xb + (size_t)fl * C_;
    acc += kern * (pf[0] * (1.f - frac) + pf[C_] * frac);
  }
  hidden[(size_t)m * C_ + tid] = (_Float16)acc;
}

// ---------------------------------------------------------------------------
extern "C" void kernel_launch(void* const* d_in, const int* in_sizes, int n_in,
                              void* d_out, int out_size, void* d_ws, size_t ws_size,
                              hipStream_t stream) {
  const float* x      = (const float*)d_in[0];
  const float* w_wave = (const float*)d_in[1];
  const float* b_wave = (const float*)d_in[2];
  const float* g_wave = (const float*)d_in[3];
  const float* w_kern = (const float*)d_in[4];
  const float* b_kern = (const float*)d_in[5];
  const float* g_kern = (const float*)d_in[6];
  const float* w_exp  = (const float*)d_in[7];
  const float* b_exp  = (const float*)d_in[8];
  const float* g_exp  = (const float*)d_in[9];
  const float* w_out  = (const float*)d_in[10];
  float* out = (float*)d_out;

  char* ws = (char*)d_ws;
  float*    ykern  = (float*)ws;                               // 16 MB
  _Float16* xh     = (_Float16*)(ws + (size_t)16 * 1024 * 1024); // 8 MB
  _Float16* wkh    = (_Float16*)(ws + (size_t)24 * 1024 * 1024); // 2 MB
  _Float16* woh    = (_Float16*)(ws + (size_t)26 * 1024 * 1024); // 2 MB
  float*    freqb  = (float*)(ws + (size_t)28 * 1024 * 1024);    // 256 KB
  float*    phaseb = freqb + (size_t)M_ * H_;
  float*    expnb  = phaseb + (size_t)M_ * H_;
  _Float16* hiddenh = xh;   // alias: xh dead after gemm1, reused for hidden

  f2h<<<(M_ * C_) / 2048, 256, 0, stream>>>(x, xh, (M_ * C_) / 8);
  f2h<<<(C_ * C_) / 2048, 256, 0, stream>>>(w_kern, wkh, (C_ * C_) / 8);
  f2h<<<(C_ * C_) / 2048, 256, 0, stream>>>(w_out, woh, (C_ * C_) / 8);

  dim3 gg(C_ / 128, M_ / 128);   // (8, 32)
  gemm_h<0><<<gg, 256, 0, stream>>>(xh, wkh, ykern, M_, C_, C_);
  token_post<<<M_, 256, 0, stream>>>(x, w_wave, b_wave, g_wave, b_kern, g_kern,
                                     w_exp, b_exp, g_exp, ykern, freqb, phaseb, expnb);
  sampler<<<M_, 1024, 0, stream>>>(x, ykern, freqb, phaseb, expnb, hiddenh);
  gemm_h<1><<<gg, 256, 0, stream>>>(hiddenh, woh, out, M_, C_, C_);
}

// Round 3
// 217.377 us; speedup vs baseline: 2.4459x; 1.2715x over previous
//
#include <hip/hip_runtime.h>
#include <hip/hip_bf16.h>
#include <math.h>

#define B_ 2
#define L_ 2048
#define C_ 1024
#define H_ 16
#define D_ 64
#define K_ 64
#define S_ 33
#define M_ (B_*L_)

typedef _Float16 half8 __attribute__((ext_vector_type(8)));
typedef _Float16 half4 __attribute__((ext_vector_type(4)));
typedef float f32x4 __attribute__((ext_vector_type(4)));

__device__ __forceinline__ float sigmoidf_(float v) { return 1.f / (1.f + __expf(-v)); }

// ---------------------------------------------------------------------------
// fp32 -> fp16 conversion, 8 elems/thread (16B stores)
// ---------------------------------------------------------------------------
__global__ __launch_bounds__(256) void f2h(const float* __restrict__ in,
                                           _Float16* __restrict__ out, int n8) {
  int i = blockIdx.x * 256 + threadIdx.x;
  if (i >= n8) return;
  const float4* p = (const float4*)in + (size_t)i * 2;
  float4 a = p[0], b = p[1];
  union { _Float16 h[8]; uint4 u; } v;
  v.h[0] = (_Float16)a.x; v.h[1] = (_Float16)a.y;
  v.h[2] = (_Float16)a.z; v.h[3] = (_Float16)a.w;
  v.h[4] = (_Float16)b.x; v.h[5] = (_Float16)b.y;
  v.h[6] = (_Float16)b.z; v.h[7] = (_Float16)b.w;
  ((uint4*)out)[i] = v.u;
}

// ---------------------------------------------------------------------------
// FP16-MFMA GEMM (m97 structure): C[m][n] = dot(A[m][:], Bw[n][:]) (+silu)
// OUTH=1 -> fp16 output, else fp32. 128x128 tile, BK=32, 256 thr.
// ---------------------------------------------------------------------------
template<int SILU, int OUTH>
__global__ __launch_bounds__(256) void gemm_h(
    const _Float16* __restrict__ A, const _Float16* __restrict__ Bw,
    void* __restrict__ Co_v, int M, int N, int Kd)
{
  __shared__ __align__(16) _Float16 As[128 * 32];
  __shared__ __align__(16) _Float16 Bs[128 * 32];
  int tid = threadIdx.x;
  int m0 = blockIdx.y * 128, n0 = blockIdx.x * 128;
  int lane = tid & 63;
  int wid = tid >> 6, wm = wid >> 1, wn = wid & 1;

  f32x4 acc[4][4];
#pragma unroll
  for (int i = 0; i < 4; i++)
#pragma unroll
    for (int j = 0; j < 4; j++)
      acc[i][j] = (f32x4){0.f, 0.f, 0.f, 0.f};

  for (int k0 = 0; k0 < Kd; k0 += 32) {
#pragma unroll
    for (int q = 0; q < 2; q++) {
      int idx = tid + q * 256;          // 0..511
      int row = idx >> 2, seg = idx & 3;
      const _Float16* ga = A  + (size_t)(m0 + row) * Kd + k0 + seg * 8;
      const _Float16* gb = Bw + (size_t)(n0 + row) * Kd + k0 + seg * 8;
      __builtin_amdgcn_global_load_lds(
          (const __attribute__((address_space(1))) unsigned int*)ga,
          (__attribute__((address_space(3))) unsigned int*)&As[idx * 8], 16, 0, 0);
      __builtin_amdgcn_global_load_lds(
          (const __attribute__((address_space(1))) unsigned int*)gb,
          (__attribute__((address_space(3))) unsigned int*)&Bs[idx * 8], 16, 0, 0);
    }
    __syncthreads();

    half8 aF[4], bF[4];
#pragma unroll
    for (int i = 0; i < 4; i++)
      aF[i] = *(const half8*)&As[(wm * 64 + i * 16 + (lane & 15)) * 32 + (lane >> 4) * 8];
#pragma unroll
    for (int j = 0; j < 4; j++)
      bF[j] = *(const half8*)&Bs[(wn * 64 + j * 16 + (lane & 15)) * 32 + (lane >> 4) * 8];
#pragma unroll
    for (int i = 0; i < 4; i++)
#pragma unroll
      for (int j = 0; j < 4; j++)
        acc[i][j] = __builtin_amdgcn_mfma_f32_16x16x32_f16(aF[i], bF[j], acc[i][j], 0, 0, 0);
    __syncthreads();
  }

  // C/D: col = lane&15, row = (lane>>4)*4 + reg
#pragma unroll
  for (int i = 0; i < 4; i++)
#pragma unroll
    for (int j = 0; j < 4; j++) {
      int col = n0 + wn * 64 + j * 16 + (lane & 15);
#pragma unroll
      for (int r = 0; r < 4; r++) {
        int row = m0 + wm * 64 + i * 16 + (lane >> 4) * 4 + r;
        float t = acc[i][j][r];
        if (SILU) t = t * sigmoidf_(t);
        if (OUTH) ((_Float16*)Co_v)[(size_t)row * N + col] = (_Float16)t;
        else      ((float*)Co_v)[(size_t)row * N + col] = t;
      }
    }
}

// ---------------------------------------------------------------------------
// Per-token postprocess (fp32 wave path — positions are precision-critical).
// ykern is fp16 raw projection in, fp16 kernel_max out.
// ---------------------------------------------------------------------------
__global__ __launch_bounds__(256) void token_post(
    const float* __restrict__ x,
    const float* __restrict__ w_wave, const float* __restrict__ b_wave,
    const float* __restrict__ g_wave,
    const float* __restrict__ b_kern, const float* __restrict__ g_kern,
    const float* __restrict__ w_exp, const float* __restrict__ b_exp,
    const float* __restrict__ g_exp,
    _Float16* __restrict__ ykern,
    float* __restrict__ freq, float* __restrict__ phase,
    float* __restrict__ expn)
{
  __shared__ float xs[C_];
  __shared__ float dots[S_];
  __shared__ float red[8];
  int m = blockIdx.x;
  int tid = threadIdx.x;
  int lane = tid & 63, wid = tid >> 6;

  ((float4*)xs)[tid] = ((const float4*)(x + (size_t)m * C_))[tid];
  __syncthreads();

  for (int n = wid; n < 33; n += 4) {
    const float* wr = (n < 32) ? (w_wave + n * C_) : w_exp;
    float s = 0.f;
    for (int k = lane; k < 256; k += 64) {
      float4 xv = ((const float4*)xs)[k];
      float4 wv = ((const float4*)wr)[k];
      s += xv.x * wv.x + xv.y * wv.y + xv.z * wv.z + xv.w * wv.w;
    }
    for (int o = 32; o; o >>= 1) s += __shfl_xor(s, o);
    if (lane == 0) dots[n] = s + ((n < 32) ? b_wave[n] : b_exp[0]);
  }
  __syncthreads();

  if (tid < 64) {
    float v = (tid < 32) ? dots[tid] : 0.f;
    float ss = v * v;
    for (int o = 32; o; o >>= 1) ss += __shfl_xor(ss, o);
    float scale = rsqrtf(ss * (1.f / 32.f) + 1e-6f);
    if (tid < 32) {
      float nv = dots[tid] * scale * g_wave[tid];
      dots[tid] = nv * sigmoidf_(nv);
    }
  }
  __syncthreads();
  if (tid < 16) {
    freq[m * H_ + tid]  = sigmoidf_(dots[tid]) * 15.f + 1.f;
    phase[m * H_ + tid] = tanhf(dots[16 + tid]) * 16.f;
  }
  if (tid == 0) {
    float y = dots[32];
    float nv = y * rsqrtf(y * y + 1e-6f) * g_exp[0];
    expn[m] = sigmoidf_(nv) * 3.5f + 0.5f;
  }

  float y[4];
  float ss = 0.f;
#pragma unroll
  for (int i = 0; i < 4; i++) {
    int c = tid + i * 256;
    y[i] = (float)ykern[(size_t)m * C_ + c] + b_kern[c];
    ss += y[i] * y[i];
  }
  for (int o = 32; o; o >>= 1) ss += __shfl_xor(ss, o);
  if (lane == 0) red[wid] = ss;
  __syncthreads();
  if (tid == 0) red[4] = rsqrtf((red[0] + red[1] + red[2] + red[3]) * (1.f / 1024.f) + 1e-6f);
  __syncthreads();
  float scale = red[4];
#pragma unroll
  for (int i = 0; i < 4; i++) {
    int c = tid + i * 256;
    float nv = y[i] * scale * g_kern[c];
    ykern[(size_t)m * C_ + c] = (_Float16)(nv * sigmoidf_(nv));
  }
}

// ---------------------------------------------------------------------------
// Sampler v3: 256 thr/block, 1 block/token (XCD-swizzled so each XCD owns
// 512 contiguous tokens -> its x window ~2.1 MB fp16 fits the 4 MiB L2).
// Phase 1: per-(h,s) kern/frac/fl into LDS (transcendentals once).
// Phase 2: thread = (h, d4): 4 contiguous d per thread, dwordx2 gathers,
// branchless (invalid s has kern=0, fl=0).
// ---------------------------------------------------------------------------
__global__ __launch_bounds__(256) void sampler(
    const _Float16* __restrict__ xh, const _Float16* __restrict__ km_g,
    const float* __restrict__ freq, const float* __restrict__ phase,
    const float* __restrict__ expn, _Float16* __restrict__ hidden)
{
  __shared__ float kw[H_][S_];
  __shared__ float fr[H_][S_];
  __shared__ int   fli[H_][S_];
  int bid = blockIdx.x;
  int m = ((bid & 7) << 9) + (bid >> 3);     // XCD swizzle (4096 = 8*512)
  int tid = threadIdx.x;
  int b = m >> 11, l = m & (L_ - 1);

  for (int i = tid; i < H_ * S_; i += 256) {
    int h = i / S_, s = i - h * S_;
    float f  = freq[m * H_ + h];
    float ph = phase[m * H_ + h];
    float e  = expn[m];
    float rel = (float)(s - 16) * f;
    float posv = (float)l + rel + ph;
    float kern = 0.f, frac = 0.f;
    int fl = 0;
    if (posv >= 0.f && posv < 2048.f) {
      float pc = fminf(posv, 2046.999f);
      fl = (int)pc;                       // pc>=0 -> trunc==floor, fl<=2046
      frac = pc - (float)fl;
      float ar = fabsf(rel);
      float idx_f = fminf(ar * (1.f / 256.f), 1.f) * 63.f;
      int i0 = (int)idx_f; if (i0 > 62) i0 = 62;
      float wc = idx_f - (float)i0;
      float k0 = (float)km_g[(size_t)m * C_ + (h << 6) + i0];
      float k1 = (float)km_g[(size_t)m * C_ + (h << 6) + i0 + 1];
      float powv = __expf(-e * __logf(1.f + ar * (1.f / 2048.f)));
      kern = (k0 * (1.f - wc) + k1 * wc) * powv;
    }
    kw[h][s] = kern; fr[h][s] = frac; fli[h][s] = fl;
  }
  __syncthreads();

  int h = tid >> 4;                 // 0..15
  int d4 = (tid & 15) << 2;         // 0,4,...,60
  const _Float16* xb = xh + (size_t)b * L_ * C_ + (h << 6) + d4;
  float acc0 = 0.f, acc1 = 0.f, acc2 = 0.f, acc3 = 0.f;
#pragma unroll 4
  for (int s = 0; s < S_; s++) {
    float kern = kw[h][s];
    float frac = fr[h][s];
    int fl = fli[h][s];
    const _Float16* pf = xb + (size_t)fl * C_;
    half4 vf = *(const half4*)pf;
    half4 vc = *(const half4*)(pf + C_);
    float wf = kern * (1.f - frac), wcf = kern * frac;
    acc0 += wf * (float)vf[0] + wcf * (float)vc[0];
    acc1 += wf * (float)vf[1] + wcf * (float)vc[1];
    acc2 += wf * (float)vf[2] + wcf * (float)vc[2];
    acc3 += wf * (float)vf[3] + wcf * (float)vc[3];
  }
  half4 o;
  o[0] = (_Float16)acc0; o[1] = (_Float16)acc1;
  o[2] = (_Float16)acc2; o[3] = (_Float16)acc3;
  *(half4*)(hidden + (size_t)m * C_ + (h << 6) + d4) = o;
}

// ---------------------------------------------------------------------------
extern "C" void kernel_launch(void* const* d_in, const int* in_sizes, int n_in,
                              void* d_out, int out_size, void* d_ws, size_t ws_size,
                              hipStream_t stream) {
  const float* x      = (const float*)d_in[0];
  const float* w_wave = (const float*)d_in[1];
  const float* b_wave = (const float*)d_in[2];
  const float* g_wave = (const float*)d_in[3];
  const float* w_kern = (const float*)d_in[4];
  const float* b_kern = (const float*)d_in[5];
  const float* g_kern = (const float*)d_in[6];
  const float* w_exp  = (const float*)d_in[7];
  const float* b_exp  = (const float*)d_in[8];
  const float* g_exp  = (const float*)d_in[9];
  const float* w_out  = (const float*)d_in[10];
  float* out = (float*)d_out;

  char* ws = (char*)d_ws;
  _Float16* ykh    = (_Float16*)ws;                              // 8 MB
  _Float16* xhp    = (_Float16*)(ws + (size_t) 8 * 1024 * 1024); // 8 MB
  _Float16* hidden = (_Float16*)(ws + (size_t)16 * 1024 * 1024); // 8 MB
  _Float16* wkh    = (_Float16*)(ws + (size_t)24 * 1024 * 1024); // 2 MB
  _Float16* woh    = (_Float16*)(ws + (size_t)26 * 1024 * 1024); // 2 MB
  float*    freqb  = (float*)(ws + (size_t)28 * 1024 * 1024);    // 256 KB
  float*    phaseb = freqb + (size_t)M_ * H_;
  float*    expnb  = phaseb + (size_t)M_ * H_;

  f2h<<<(M_ * C_) / 2048, 256, 0, stream>>>(x, xhp, (M_ * C_) / 8);
  f2h<<<(C_ * C_) / 2048, 256, 0, stream>>>(w_kern, wkh, (C_ * C_) / 8);
  f2h<<<(C_ * C_) / 2048, 256, 0, stream>>>(w_out, woh, (C_ * C_) / 8);

  dim3 gg(C_ / 128, M_ / 128);   // (8, 32)
  gemm_h<0,1><<<gg, 256, 0, stream>>>(xhp, wkh, ykh, M_, C_, C_);
  token_post<<<M_, 256, 0, stream>>>(x, w_wave, b_wave, g_wave, b_kern, g_kern,
                                     w_exp, b_exp, g_exp, ykh, freqb, phaseb, expnb);
  sampler<<<M_, 256, 0, stream>>>(xhp, ykh, freqb, phaseb, expnb, hidden);
  gemm_h<1,0><<<gg, 256, 0, stream>>>(hidden, woh, out, M_, C_, C_);
}

// Round 9
// 190.483 us; speedup vs baseline: 2.7913x; 1.1412x over previous
//
#include <hip/hip_runtime.h>
#include <hip/hip_bf16.h>
#include <math.h>

#define B_ 2
#define L_ 2048
#define C_ 1024
#define H_ 16
#define D_ 64
#define K_ 64
#define S_ 33
#define M_ (B_*L_)

typedef _Float16 half8 __attribute__((ext_vector_type(8)));
typedef float f32x4 __attribute__((ext_vector_type(4)));

__device__ __forceinline__ float sigmoidf_(float v) { return 1.f / (1.f + __expf(-v)); }

// ---------------------------------------------------------------------------
// Weight conversion: w_kern and w_out -> fp16, one kernel.
// 1024x1024 each = 131072 half8 per matrix.
// ---------------------------------------------------------------------------
__global__ __launch_bounds__(256) void conv_w(
    const float* __restrict__ w_kern, const float* __restrict__ w_out,
    _Float16* __restrict__ wkh, _Float16* __restrict__ woh)
{
  int i = blockIdx.x * 256 + threadIdx.x;        // 0 .. 262143
  const float* src; _Float16* dst; int j;
  if (i < 131072) { src = w_kern; dst = wkh; j = i; }
  else            { src = w_out;  dst = woh; j = i - 131072; }
  float4 a = ((const float4*)src)[j * 2];
  float4 b = ((const float4*)src)[j * 2 + 1];
  half8 v;
  v[0] = (_Float16)a.x; v[1] = (_Float16)a.y; v[2] = (_Float16)a.z; v[3] = (_Float16)a.w;
  v[4] = (_Float16)b.x; v[5] = (_Float16)b.y; v[6] = (_Float16)b.z; v[7] = (_Float16)b.w;
  ((half8*)dst)[j] = v;
}

// ---------------------------------------------------------------------------
// prep: 4 tokens/block (256 thr, wave = token). Reads x (fp32) once:
//  - writes xh (fp16) for the GEMMs/sampler
//  - computes 33 fp32 dots (wave proj + exp proj), rmsnorm+silu, transforms
//    -> freq/phase/expn   (fp32 path: sample positions are precision-critical)
// ---------------------------------------------------------------------------
__global__ __launch_bounds__(256) void prep(
    const float* __restrict__ x,
    const float* __restrict__ w_wave, const float* __restrict__ b_wave,
    const float* __restrict__ g_wave,
    const float* __restrict__ w_exp, const float* __restrict__ b_exp,
    const float* __restrict__ g_exp,
    _Float16* __restrict__ xh,
    float* __restrict__ freq, float* __restrict__ phase, float* __restrict__ expn)
{
  __shared__ float xs[4 * C_];      // 16 KB
  __shared__ float dots[4][S_];
  int bid = blockIdx.x;             // 0..1023
  int tid = threadIdx.x;
  int lane = tid & 63, wv = tid >> 6;
  int m0 = bid * 4;

#pragma unroll
  for (int q = 0; q < 4; q++) {
    int idx = tid + q * 256;        // float4 index 0..1023
    ((float4*)xs)[idx] = ((const float4*)(x + (size_t)m0 * C_))[idx];
  }
  __syncthreads();

  // xh conversion (4 rows = 512 half8)
#pragma unroll
  for (int q = 0; q < 2; q++) {
    int i8 = tid + q * 256;
    float4 a = ((const float4*)xs)[i8 * 2];
    float4 b = ((const float4*)xs)[i8 * 2 + 1];
    half8 v;
    v[0] = (_Float16)a.x; v[1] = (_Float16)a.y; v[2] = (_Float16)a.z; v[3] = (_Float16)a.w;
    v[4] = (_Float16)b.x; v[5] = (_Float16)b.y; v[6] = (_Float16)b.z; v[7] = (_Float16)b.w;
    ((half8*)(xh + (size_t)m0 * C_))[i8] = v;
  }

  // each wave: all 33 dots for its token
  const float* xrow = xs + wv * C_;
  for (int n = 0; n < 33; n++) {
    const float* wr = (n < 32) ? (w_wave + n * C_) : w_exp;
    float s = 0.f;
#pragma unroll
    for (int q = 0; q < 4; q++) {
      int k4 = lane + q * 64;
      float4 xv = ((const float4*)xrow)[k4];
      float4 wv4 = ((const float4*)wr)[k4];
      s += xv.x * wv4.x + xv.y * wv4.y + xv.z * wv4.z + xv.w * wv4.w;
    }
    for (int o = 32; o; o >>= 1) s += __shfl_xor(s, o);
    if (lane == 0) dots[wv][n] = s + ((n < 32) ? b_wave[n] : b_exp[0]);
  }
  __syncthreads();

  int m = m0 + wv;
  float v = (lane < 32) ? dots[wv][lane] : 0.f;
  float ss = v * v;
  for (int o = 32; o; o >>= 1) ss += __shfl_xor(ss, o);
  float scale = rsqrtf(ss * (1.f / 32.f) + 1e-6f);
  if (lane < 32) {
    float nv = dots[wv][lane] * scale * g_wave[lane];
    float sv = nv * sigmoidf_(nv);
    if (lane < 16) freq[m * H_ + lane] = sigmoidf_(sv) * 15.f + 1.f;
    else           phase[m * H_ + lane - 16] = tanhf(sv) * 16.f;
  }
  if (lane == 0) {
    float y = dots[wv][32];
    float nv = y * rsqrtf(y * y + 1e-6f) * g_exp[0];
    expn[m] = sigmoidf_(nv) * 3.5f + 0.5f;
  }
}

// ---------------------------------------------------------------------------
// FP16-MFMA GEMM, 64x128 tile (512 blocks -> 2/CU), BK=32, 256 thr (4 waves,
// wave w owns cols [w*32, w*32+32) of all 64 rows).
// LDS bank-conflict fix (rule #21): linear global_load_lds dest + SOURCE-side
// seg swizzle seg' = seg ^ (row&3); ds_read applies the same involution.
// ---------------------------------------------------------------------------
template<int SILU, int OUTH>
__global__ __launch_bounds__(256) void gemm_h(
    const _Float16* __restrict__ A, const _Float16* __restrict__ Bw,
    void* __restrict__ Co_v, int M, int N, int Kd)
{
  __shared__ __align__(16) _Float16 As[64 * 32];    // 4 KB
  __shared__ __align__(16) _Float16 Bs[128 * 32];   // 8 KB
  int tid = threadIdx.x;
  int m0 = blockIdx.y * 64, n0 = blockIdx.x * 128;
  int lane = tid & 63;
  int w = tid >> 6;

  f32x4 acc[4][2];
#pragma unroll
  for (int i = 0; i < 4; i++)
#pragma unroll
    for (int j = 0; j < 2; j++)
      acc[i][j] = (f32x4){0.f, 0.f, 0.f, 0.f};

  for (int k0 = 0; k0 < Kd; k0 += 32) {
    {   // A tile: 64 rows x 32 -> 256 x 16B, one load/thread
      int row = tid >> 2, seg = tid & 3;
      int sseg = seg ^ (row & 3);
      const _Float16* ga = A + (size_t)(m0 + row) * Kd + k0 + sseg * 8;
      __builtin_amdgcn_global_load_lds(
          (const __attribute__((address_space(1))) unsigned int*)ga,
          (__attribute__((address_space(3))) unsigned int*)&As[tid * 8], 16, 0, 0);
    }
#pragma unroll
    for (int q = 0; q < 2; q++) {   // B tile: 128 rows x 32 -> 512 x 16B
      int idx = tid + q * 256;
      int row = idx >> 2, seg = idx & 3;
      int sseg = seg ^ (row & 3);
      const _Float16* gb = Bw + (size_t)(n0 + row) * Kd + k0 + sseg * 8;
      __builtin_amdgcn_global_load_lds(
          (const __attribute__((address_space(1))) unsigned int*)gb,
          (__attribute__((address_space(3))) unsigned int*)&Bs[idx * 8], 16, 0, 0);
    }
    __syncthreads();

    half8 aF[4], bF[2];
#pragma unroll
    for (int i = 0; i < 4; i++) {
      int ar = i * 16 + (lane & 15);
      int ac = (lane >> 4) ^ (ar & 3);
      aF[i] = *(const half8*)&As[ar * 32 + ac * 8];
    }
#pragma unroll
    for (int j = 0; j < 2; j++) {
      int br = w * 32 + j * 16 + (lane & 15);
      int bc = (lane >> 4) ^ (br & 3);
      bF[j] = *(const half8*)&Bs[br * 32 + bc * 8];
    }
#pragma unroll
    for (int i = 0; i < 4; i++)
#pragma unroll
      for (int j = 0; j < 2; j++)
        acc[i][j] = __builtin_amdgcn_mfma_f32_16x16x32_f16(aF[i], bF[j], acc[i][j], 0, 0, 0);
    __syncthreads();
  }

  // C/D: col = lane&15, row = (lane>>4)*4 + reg
#pragma unroll
  for (int i = 0; i < 4; i++)
#pragma unroll
    for (int j = 0; j < 2; j++) {
      int col = n0 + w * 32 + j * 16 + (lane & 15);
#pragma unroll
      for (int r = 0; r < 4; r++) {
        int row = m0 + i * 16 + (lane >> 4) * 4 + r;
        float t = acc[i][j][r];
        if (SILU) t = t * sigmoidf_(t);
        if (OUTH) ((_Float16*)Co_v)[(size_t)row * N + col] = (_Float16)t;
        else      ((float*)Co_v)[(size_t)row * N + col] = t;
      }
    }
}

// ---------------------------------------------------------------------------
// Sampler v4: 256 thr/block, 2 tokens/block (sub = tid>>7), XCD-swizzled so
// each XCD owns 512 contiguous tokens (x window ~2.2 MB fp16 fits 4 MiB L2).
//  A) fused kern rmsnorm+silu: ykern_raw(fp16) -> km in LDS
//  B) phase 1: per-(h,s) kern/frac/fl (transcendentals once)
//  C) phase 2: thread=(h,d8): half8 16B gathers, branchless lerp-accumulate
// ---------------------------------------------------------------------------
__global__ __launch_bounds__(256) void sampler(
    const _Float16* __restrict__ xh, const _Float16* __restrict__ ykr,
    const float* __restrict__ b_kern, const float* __restrict__ g_kern,
    const float* __restrict__ freq, const float* __restrict__ phase,
    const float* __restrict__ expn, _Float16* __restrict__ hidden)
{
  __shared__ float km[2][C_];        // 8 KB
  __shared__ float kw[2][H_][S_];
  __shared__ float fr[2][H_][S_];
  __shared__ int   fli[2][H_][S_];
  __shared__ float red2[2][2];
  int bid = blockIdx.x;                          // 0..2047
  int pair = ((bid & 7) << 8) + (bid >> 3);      // XCD swizzle (2048 = 8*256)
  int tid = threadIdx.x;
  int sub = tid >> 7, t = tid & 127;
  int m = pair * 2 + sub;
  int b = m >> 11, l = m & (L_ - 1);
  int lane = tid & 63;

  // A) kern rmsnorm + silu -> km[sub][*]
  float yv[8];
  {
    half8 hv = *(const half8*)(ykr + (size_t)m * C_ + t * 8);
    float ss = 0.f;
#pragma unroll
    for (int j = 0; j < 8; j++) {
      yv[j] = (float)hv[j] + b_kern[t * 8 + j];
      ss += yv[j] * yv[j];
    }
    for (int o = 32; o; o >>= 1) ss += __shfl_xor(ss, o);
    if (lane == 0) red2[sub][t >> 6] = ss;
  }
  __syncthreads();
  {
    float scale = rsqrtf((red2[sub][0] + red2[sub][1]) * (1.f / 1024.f) + 1e-6f);
#pragma unroll
    for (int j = 0; j < 8; j++) {
      float nv = yv[j] * scale * g_kern[t * 8 + j];
      km[sub][t * 8 + j] = nv * sigmoidf_(nv);
    }
  }
  __syncthreads();

  // B) per-(h,s) sample params
  float e = expn[m];
  for (int i = t; i < H_ * S_; i += 128) {
    int h = i / S_, s = i - h * S_;
    float f  = freq[m * H_ + h];
    float ph = phase[m * H_ + h];
    float rel = (float)(s - 16) * f;
    float posv = (float)l + rel + ph;
    float kern = 0.f, frac = 0.f;
    int fl = 0;
    if (posv >= 0.f && posv < 2048.f) {
      float pc = fminf(posv, 2046.999f);
      fl = (int)pc;                      // pc>=0 -> trunc==floor, fl<=2046
      frac = pc - (float)fl;
      float ar = fabsf(rel);
      float idx_f = fminf(ar * (1.f / 256.f), 1.f) * 63.f;
      int i0 = (int)idx_f; if (i0 > 62) i0 = 62;
      float wc = idx_f - (float)i0;
      float k0 = km[sub][(h << 6) + i0];
      float k1 = km[sub][(h << 6) + i0 + 1];
      float powv = __expf(-e * __logf(1.f + ar * (1.f / 2048.f)));
      kern = (k0 * (1.f - wc) + k1 * wc) * powv;
    }
    kw[sub][h][s] = kern; fr[sub][h][s] = frac; fli[sub][h][s] = fl;
  }
  __syncthreads();

  // C) gather + lerp + accumulate
  int h = t >> 3, d8 = (t & 7) << 3;
  const _Float16* xb = xh + (size_t)b * L_ * C_ + (h << 6) + d8;
  float acc[8] = {0.f, 0.f, 0.f, 0.f, 0.f, 0.f, 0.f, 0.f};
#pragma unroll 4
  for (int s = 0; s < S_; s++) {
    float kern = kw[sub][h][s];
    float frac = fr[sub][h][s];
    int fl = fli[sub][h][s];
    const _Float16* pf = xb + (size_t)fl * C_;
    half8 vf = *(const half8*)pf;
    half8 vc = *(const half8*)(pf + C_);
    float wf = kern * (1.f - frac), wcf = kern * frac;
#pragma unroll
    for (int j = 0; j < 8; j++)
      acc[j] += wf * (float)vf[j] + wcf * (float)vc[j];
  }
  half8 o8;
#pragma unroll
  for (int j = 0; j < 8; j++) o8[j] = (_Float16)acc[j];
  *(half8*)(hidden + (size_t)m * C_ + (h << 6) + d8) = o8;
}

// ---------------------------------------------------------------------------
extern "C" void kernel_launch(void* const* d_in, const int* in_sizes, int n_in,
                              void* d_out, int out_size, void* d_ws, size_t ws_size,
                              hipStream_t stream) {
  const float* x      = (const float*)d_in[0];
  const float* w_wave = (const float*)d_in[1];
  const float* b_wave = (const float*)d_in[2];
  const float* g_wave = (const float*)d_in[3];
  const float* w_kern = (const float*)d_in[4];
  const float* b_kern = (const float*)d_in[5];
  const float* g_kern = (const float*)d_in[6];
  const float* w_exp  = (const float*)d_in[7];
  const float* b_exp  = (const float*)d_in[8];
  const float* g_exp  = (const float*)d_in[9];
  const float* w_out  = (const float*)d_in[10];
  float* out = (float*)d_out;

  char* ws = (char*)d_ws;
  _Float16* ykh    = (_Float16*)ws;                              // 8 MB (raw proj)
  _Float16* xhp    = (_Float16*)(ws + (size_t) 8 * 1024 * 1024); // 8 MB
  _Float16* hidden = (_Float16*)(ws + (size_t)16 * 1024 * 1024); // 8 MB
  _Float16* wkh    = (_Float16*)(ws + (size_t)24 * 1024 * 1024); // 2 MB
  _Float16* woh    = (_Float16*)(ws + (size_t)26 * 1024 * 1024); // 2 MB
  float*    freqb  = (float*)(ws + (size_t)28 * 1024 * 1024);
  float*    phaseb = freqb + (size_t)M_ * H_;
  float*    expnb  = phaseb + (size_t)M_ * H_;

  conv_w<<<1024, 256, 0, stream>>>(w_kern, w_out, wkh, woh);
  prep<<<M_ / 4, 256, 0, stream>>>(x, w_wave, b_wave, g_wave, w_exp, b_exp, g_exp,
                                   xhp, freqb, phaseb, expnb);
  dim3 gg(C_ / 128, M_ / 64);   // (8, 64) = 512 blocks
  gemm_h<0,1><<<gg, 256, 0, stream>>>(xhp, wkh, ykh, M_, C_, C_);
  sampler<<<M_ / 2, 256, 0, stream>>>(xhp, ykh, b_kern, g_kern,
                                      freqb, phaseb, expnb, hidden);
  gemm_h<1,0><<<gg, 256, 0, stream>>>(hidden, woh, out, M_, C_, C_);
}

// Round 10
// 187.044 us; speedup vs baseline: 2.8426x; 1.0184x over previous
//
#include <hip/hip_runtime.h>
#include <hip/hip_bf16.h>
#include <math.h>

#define B_ 2
#define L_ 2048
#define C_ 1024
#define H_ 16
#define D_ 64
#define K_ 64
#define S_ 33
#define M_ (B_*L_)

typedef _Float16 half8 __attribute__((ext_vector_type(8)));
typedef float f32x4 __attribute__((ext_vector_type(4)));

__device__ __forceinline__ float sigmoidf_(float v) { return 1.f / (1.f + __expf(-v)); }

// ---------------------------------------------------------------------------
// Weight conversion: w_kern and w_out -> fp16, one kernel.
// ---------------------------------------------------------------------------
__global__ __launch_bounds__(256) void conv_w(
    const float* __restrict__ w_kern, const float* __restrict__ w_out,
    _Float16* __restrict__ wkh, _Float16* __restrict__ woh)
{
  int i = blockIdx.x * 256 + threadIdx.x;        // 0 .. 262143
  const float* src; _Float16* dst; int j;
  if (i < 131072) { src = w_kern; dst = wkh; j = i; }
  else            { src = w_out;  dst = woh; j = i - 131072; }
  float4 a = ((const float4*)src)[j * 2];
  float4 b = ((const float4*)src)[j * 2 + 1];
  half8 v;
  v[0] = (_Float16)a.x; v[1] = (_Float16)a.y; v[2] = (_Float16)a.z; v[3] = (_Float16)a.w;
  v[4] = (_Float16)b.x; v[5] = (_Float16)b.y; v[6] = (_Float16)b.z; v[7] = (_Float16)b.w;
  ((half8*)dst)[j] = v;
}

// ---------------------------------------------------------------------------
// prep: 4 tokens/block (256 thr, wave = token). Reads x (fp32) once:
// writes xh (fp16); computes wave/exp dots fp32 -> freq/phase/expn
// (positions are precision-critical, stays fp32).
// ---------------------------------------------------------------------------
__global__ __launch_bounds__(256) void prep(
    const float* __restrict__ x,
    const float* __restrict__ w_wave, const float* __restrict__ b_wave,
    const float* __restrict__ g_wave,
    const float* __restrict__ w_exp, const float* __restrict__ b_exp,
    const float* __restrict__ g_exp,
    _Float16* __restrict__ xh,
    float* __restrict__ freq, float* __restrict__ phase, float* __restrict__ expn)
{
  __shared__ float xs[4 * C_];      // 16 KB
  __shared__ float dots[4][S_];
  int bid = blockIdx.x;             // 0..1023
  int tid = threadIdx.x;
  int lane = tid & 63, wv = tid >> 6;
  int m0 = bid * 4;

#pragma unroll
  for (int q = 0; q < 4; q++) {
    int idx = tid + q * 256;
    ((float4*)xs)[idx] = ((const float4*)(x + (size_t)m0 * C_))[idx];
  }
  __syncthreads();

#pragma unroll
  for (int q = 0; q < 2; q++) {
    int i8 = tid + q * 256;
    float4 a = ((const float4*)xs)[i8 * 2];
    float4 b = ((const float4*)xs)[i8 * 2 + 1];
    half8 v;
    v[0] = (_Float16)a.x; v[1] = (_Float16)a.y; v[2] = (_Float16)a.z; v[3] = (_Float16)a.w;
    v[4] = (_Float16)b.x; v[5] = (_Float16)b.y; v[6] = (_Float16)b.z; v[7] = (_Float16)b.w;
    ((half8*)(xh + (size_t)m0 * C_))[i8] = v;
  }

  const float* xrow = xs + wv * C_;
  for (int n = 0; n < 33; n++) {
    const float* wr = (n < 32) ? (w_wave + n * C_) : w_exp;
    float s = 0.f;
#pragma unroll
    for (int q = 0; q < 4; q++) {
      int k4 = lane + q * 64;
      float4 xv = ((const float4*)xrow)[k4];
      float4 wv4 = ((const float4*)wr)[k4];
      s += xv.x * wv4.x + xv.y * wv4.y + xv.z * wv4.z + xv.w * wv4.w;
    }
    for (int o = 32; o; o >>= 1) s += __shfl_xor(s, o);
    if (lane == 0) dots[wv][n] = s + ((n < 32) ? b_wave[n] : b_exp[0]);
  }
  __syncthreads();

  int m = m0 + wv;
  float v = (lane < 32) ? dots[wv][lane] : 0.f;
  float ss = v * v;
  for (int o = 32; o; o >>= 1) ss += __shfl_xor(ss, o);
  float scale = rsqrtf(ss * (1.f / 32.f) + 1e-6f);
  if (lane < 32) {
    float nv = dots[wv][lane] * scale * g_wave[lane];
    float sv = nv * sigmoidf_(nv);
    if (lane < 16) freq[m * H_ + lane] = sigmoidf_(sv) * 15.f + 1.f;
    else           phase[m * H_ + lane - 16] = tanhf(sv) * 16.f;
  }
  if (lane == 0) {
    float y = dots[wv][32];
    float nv = y * rsqrtf(y * y + 1e-6f) * g_exp[0];
    expn[m] = sigmoidf_(nv) * 3.5f + 0.5f;
  }
}

// ---------------------------------------------------------------------------
// FP16-MFMA GEMM, 128x128 tile, split-K=2 (blockIdx.z), BK=32, 256 thr
// (4 waves 2x2 of 64x64; 16 MFMA : 8 ds_read_b128 per wave-K-step = 2:1).
// Grid (N/128, M/128, 2) = 512 blocks -> 2 blocks/CU, 8 waves/CU.
// LDS swizzle (rule #21): linear global_load_lds dest + SOURCE-side
// seg' = seg ^ (row&3); ds_read applies the same involution.
// Writes fp16 PARTIALS (no activation): Cp[z*M*N + row*N + col].
// ---------------------------------------------------------------------------
__global__ __launch_bounds__(256) void gemm_sk(
    const _Float16* __restrict__ A, const _Float16* __restrict__ Bw,
    _Float16* __restrict__ Cp, int M, int N, int Kd)
{
  __shared__ __align__(16) _Float16 As[128 * 32];   // 8 KB
  __shared__ __align__(16) _Float16 Bs[128 * 32];   // 8 KB
  int tid = threadIdx.x;
  int m0 = blockIdx.y * 128, n0 = blockIdx.x * 128;
  int z = blockIdx.z;
  int kbase = z * (Kd >> 1);
  int lane = tid & 63;
  int wid = tid >> 6, wm = wid >> 1, wn = wid & 1;

  f32x4 acc[4][4];
#pragma unroll
  for (int i = 0; i < 4; i++)
#pragma unroll
    for (int j = 0; j < 4; j++)
      acc[i][j] = (f32x4){0.f, 0.f, 0.f, 0.f};

  for (int k0 = 0; k0 < (Kd >> 1); k0 += 32) {
#pragma unroll
    for (int q = 0; q < 2; q++) {
      int idx = tid + q * 256;          // 0..511
      int row = idx >> 2, seg = idx & 3;
      int sseg = seg ^ (row & 3);
      const _Float16* ga = A  + (size_t)(m0 + row) * Kd + kbase + k0 + sseg * 8;
      const _Float16* gb = Bw + (size_t)(n0 + row) * Kd + kbase + k0 + sseg * 8;
      __builtin_amdgcn_global_load_lds(
          (const __attribute__((address_space(1))) unsigned int*)ga,
          (__attribute__((address_space(3))) unsigned int*)&As[idx * 8], 16, 0, 0);
      __builtin_amdgcn_global_load_lds(
          (const __attribute__((address_space(1))) unsigned int*)gb,
          (__attribute__((address_space(3))) unsigned int*)&Bs[idx * 8], 16, 0, 0);
    }
    __syncthreads();

    half8 aF[4], bF[4];
#pragma unroll
    for (int i = 0; i < 4; i++) {
      int ar = wm * 64 + i * 16 + (lane & 15);
      int ac = (lane >> 4) ^ (ar & 3);
      aF[i] = *(const half8*)&As[ar * 32 + ac * 8];
    }
#pragma unroll
    for (int j = 0; j < 4; j++) {
      int br = wn * 64 + j * 16 + (lane & 15);
      int bc = (lane >> 4) ^ (br & 3);
      bF[j] = *(const half8*)&Bs[br * 32 + bc * 8];
    }
#pragma unroll
    for (int i = 0; i < 4; i++)
#pragma unroll
      for (int j = 0; j < 4; j++)
        acc[i][j] = __builtin_amdgcn_mfma_f32_16x16x32_f16(aF[i], bF[j], acc[i][j], 0, 0, 0);
    __syncthreads();
  }

  // C/D: col = lane&15, row = (lane>>4)*4 + reg
  _Float16* Cz = Cp + (size_t)z * M * N;
#pragma unroll
  for (int i = 0; i < 4; i++)
#pragma unroll
    for (int j = 0; j < 4; j++) {
      int col = n0 + wn * 64 + j * 16 + (lane & 15);
#pragma unroll
      for (int r = 0; r < 4; r++) {
        int row = m0 + wm * 64 + i * 16 + (lane >> 4) * 4 + r;
        Cz[(size_t)row * N + col] = (_Float16)acc[i][j][r];
      }
    }
}

// ---------------------------------------------------------------------------
// epi: out = silu(hp0 + hp1), fp32. 8 elems/thread.
// ---------------------------------------------------------------------------
__global__ __launch_bounds__(256) void epi(
    const _Float16* __restrict__ hp, float* __restrict__ out)
{
  int i = blockIdx.x * 256 + threadIdx.x;   // 0 .. 524287 (half8 units)
  half8 a = ((const half8*)hp)[i];
  half8 b = ((const half8*)(hp + (size_t)M_ * C_))[i];
  float o[8];
#pragma unroll
  for (int j = 0; j < 8; j++) {
    float t = (float)a[j] + (float)b[j];
    o[j] = t * sigmoidf_(t);
  }
  ((float4*)out)[i * 2]     = make_float4(o[0], o[1], o[2], o[3]);
  ((float4*)out)[i * 2 + 1] = make_float4(o[4], o[5], o[6], o[7]);
}

// ---------------------------------------------------------------------------
// Sampler: 256 thr/block, 2 tokens/block, XCD-swizzled.
//  A) sum split-K halves + bias -> rmsnorm+silu -> km in LDS
//  B) per-(h,s) kern/frac/fl (transcendentals once)
//  C) thread=(h,d8): half8 16B gathers, branchless lerp-accumulate
// ---------------------------------------------------------------------------
__global__ __launch_bounds__(256) void sampler(
    const _Float16* __restrict__ xh, const _Float16* __restrict__ ykp,
    const float* __restrict__ b_kern, const float* __restrict__ g_kern,
    const float* __restrict__ freq, const float* __restrict__ phase,
    const float* __restrict__ expn, _Float16* __restrict__ hidden)
{
  __shared__ float km[2][C_];        // 8 KB
  __shared__ float kw[2][H_][S_];
  __shared__ float fr[2][H_][S_];
  __shared__ int   fli[2][H_][S_];
  __shared__ float red2[2][2];
  int bid = blockIdx.x;                          // 0..2047
  int pair = ((bid & 7) << 8) + (bid >> 3);      // XCD swizzle (2048 = 8*256)
  int tid = threadIdx.x;
  int sub = tid >> 7, t = tid & 127;
  int m = pair * 2 + sub;
  int b = m >> 11, l = m & (L_ - 1);
  int lane = tid & 63;

  // A) split-K sum + bias + rmsnorm + silu -> km[sub][*]
  float yv[8];
  {
    half8 h0 = *(const half8*)(ykp + (size_t)m * C_ + t * 8);
    half8 h1 = *(const half8*)(ykp + (size_t)M_ * C_ + (size_t)m * C_ + t * 8);
    float ss = 0.f;
#pragma unroll
    for (int j = 0; j < 8; j++) {
      yv[j] = (float)h0[j] + (float)h1[j] + b_kern[t * 8 + j];
      ss += yv[j] * yv[j];
    }
    for (int o = 32; o; o >>= 1) ss += __shfl_xor(ss, o);
    if (lane == 0) red2[sub][t >> 6] = ss;
  }
  __syncthreads();
  {
    float scale = rsqrtf((red2[sub][0] + red2[sub][1]) * (1.f / 1024.f) + 1e-6f);
#pragma unroll
    for (int j = 0; j < 8; j++) {
      float nv = yv[j] * scale * g_kern[t * 8 + j];
      km[sub][t * 8 + j] = nv * sigmoidf_(nv);
    }
  }
  __syncthreads();

  // B) per-(h,s) sample params
  float e = expn[m];
  for (int i = t; i < H_ * S_; i += 128) {
    int h = i / S_, s = i - h * S_;
    float f  = freq[m * H_ + h];
    float ph = phase[m * H_ + h];
    float rel = (float)(s - 16) * f;
    float posv = (float)l + rel + ph;
    float kern = 0.f, frac = 0.f;
    int fl = 0;
    if (posv >= 0.f && posv < 2048.f) {
      float pc = fminf(posv, 2046.999f);
      fl = (int)pc;                      // pc>=0 -> trunc==floor, fl<=2046
      frac = pc - (float)fl;
      float ar = fabsf(rel);
      float idx_f = fminf(ar * (1.f / 256.f), 1.f) * 63.f;
      int i0 = (int)idx_f; if (i0 > 62) i0 = 62;
      float wc = idx_f - (float)i0;
      float k0 = km[sub][(h << 6) + i0];
      float k1 = km[sub][(h << 6) + i0 + 1];
      float powv = __expf(-e * __logf(1.f + ar * (1.f / 2048.f)));
      kern = (k0 * (1.f - wc) + k1 * wc) * powv;
    }
    kw[sub][h][s] = kern; fr[sub][h][s] = frac; fli[sub][h][s] = fl;
  }
  __syncthreads();

  // C) gather + lerp + accumulate
  int h = t >> 3, d8 = (t & 7) << 3;
  const _Float16* xb = xh + (size_t)b * L_ * C_ + (h << 6) + d8;
  float acc[8] = {0.f, 0.f, 0.f, 0.f, 0.f, 0.f, 0.f, 0.f};
#pragma unroll 4
  for (int s = 0; s < S_; s++) {
    float kern = kw[sub][h][s];
    float frac = fr[sub][h][s];
    int fl = fli[sub][h][s];
    const _Float16* pf = xb + (size_t)fl * C_;
    half8 vf = *(const half8*)pf;
    half8 vc = *(const half8*)(pf + C_);
    float wf = kern * (1.f - frac), wcf = kern * frac;
#pragma unroll
    for (int j = 0; j < 8; j++)
      acc[j] += wf * (float)vf[j] + wcf * (float)vc[j];
  }
  half8 o8;
#pragma unroll
  for (int j = 0; j < 8; j++) o8[j] = (_Float16)acc[j];
  *(half8*)(hidden + (size_t)m * C_ + (h << 6) + d8) = o8;
}

// ---------------------------------------------------------------------------
extern "C" void kernel_launch(void* const* d_in, const int* in_sizes, int n_in,
                              void* d_out, int out_size, void* d_ws, size_t ws_size,
                              hipStream_t stream) {
  const float* x      = (const float*)d_in[0];
  const float* w_wave = (const float*)d_in[1];
  const float* b_wave = (const float*)d_in[2];
  const float* g_wave = (const float*)d_in[3];
  const float* w_kern = (const float*)d_in[4];
  const float* b_kern = (const float*)d_in[5];
  const float* g_kern = (const float*)d_in[6];
  const float* w_exp  = (const float*)d_in[7];
  const float* b_exp  = (const float*)d_in[8];
  const float* g_exp  = (const float*)d_in[9];
  const float* w_out  = (const float*)d_in[10];
  float* out = (float*)d_out;

  char* ws = (char*)d_ws;
  _Float16* xhp    = (_Float16*)ws;                              //  0..8  MB
  _Float16* hidden = (_Float16*)(ws + (size_t) 8 * 1024 * 1024); //  8..16 MB
  _Float16* ykp    = (_Float16*)(ws + (size_t)16 * 1024 * 1024); // 16..32 MB (2 halves)
  _Float16* hp     = (_Float16*)(ws + (size_t)32 * 1024 * 1024); // 32..48 MB (2 halves)
  _Float16* wkh    = (_Float16*)(ws + (size_t)48 * 1024 * 1024); // 48..50 MB
  _Float16* woh    = (_Float16*)(ws + (size_t)50 * 1024 * 1024); // 50..52 MB
  float*    freqb  = (float*)(ws + (size_t)52 * 1024 * 1024);
  float*    phaseb = freqb + (size_t)M_ * H_;
  float*    expnb  = phaseb + (size_t)M_ * H_;

  conv_w<<<1024, 256, 0, stream>>>(w_kern, w_out, wkh, woh);
  prep<<<M_ / 4, 256, 0, stream>>>(x, w_wave, b_wave, g_wave, w_exp, b_exp, g_exp,
                                   xhp, freqb, phaseb, expnb);
  dim3 gg(C_ / 128, M_ / 128, 2);   // (8, 32, 2) = 512 blocks
  gemm_sk<<<gg, 256, 0, stream>>>(xhp, wkh, ykp, M_, C_, C_);
  sampler<<<M_ / 2, 256, 0, stream>>>(xhp, ykp, b_kern, g_kern,
                                      freqb, phaseb, expnb, hidden);
  gemm_sk<<<gg, 256, 0, stream>>>(hidden, woh, hp, M_, C_, C_);
  epi<<<(M_ * C_) / 2048, 256, 0, stream>>>(hp, out);
}

// Round 13
// 181.845 us; speedup vs baseline: 2.9239x; 1.0286x over previous
//
#include <hip/hip_runtime.h>
#include <hip/hip_bf16.h>
#include <math.h>

#define B_ 2
#define L_ 2048
#define C_ 1024
#define H_ 16
#define D_ 64
#define K_ 64
#define S_ 33
#define M_ (B_*L_)

typedef _Float16 half8 __attribute__((ext_vector_type(8)));
typedef float f32x4 __attribute__((ext_vector_type(4)));

__device__ __forceinline__ float sigmoidf_(float v) { return 1.f / (1.f + __expf(-v)); }

// ---------------------------------------------------------------------------
// Weight conversion: w_kern and w_out -> fp16, one kernel.
// ---------------------------------------------------------------------------
__global__ __launch_bounds__(256) void conv_w(
    const float* __restrict__ w_kern, const float* __restrict__ w_out,
    _Float16* __restrict__ wkh, _Float16* __restrict__ woh)
{
  int i = blockIdx.x * 256 + threadIdx.x;        // 0 .. 262143
  const float* src; _Float16* dst; int j;
  if (i < 131072) { src = w_kern; dst = wkh; j = i; }
  else            { src = w_out;  dst = woh; j = i - 131072; }
  float4 a = ((const float4*)src)[j * 2];
  float4 b = ((const float4*)src)[j * 2 + 1];
  half8 v;
  v[0] = (_Float16)a.x; v[1] = (_Float16)a.y; v[2] = (_Float16)a.z; v[3] = (_Float16)a.w;
  v[4] = (_Float16)b.x; v[5] = (_Float16)b.y; v[6] = (_Float16)b.z; v[7] = (_Float16)b.w;
  ((half8*)dst)[j] = v;
}

// ---------------------------------------------------------------------------
// prep: 4 tokens/block (256 thr, wave = token). Reads x (fp32) once:
// writes xh (fp16); computes wave/exp dots fp32 -> freq/phase/expn
// (positions are precision-critical, stays fp32).
// ---------------------------------------------------------------------------
__global__ __launch_bounds__(256) void prep(
    const float* __restrict__ x,
    const float* __restrict__ w_wave, const float* __restrict__ b_wave,
    const float* __restrict__ g_wave,
    const float* __restrict__ w_exp, const float* __restrict__ b_exp,
    const float* __restrict__ g_exp,
    _Float16* __restrict__ xh,
    float* __restrict__ freq, float* __restrict__ phase, float* __restrict__ expn)
{
  __shared__ float xs[4 * C_];      // 16 KB
  __shared__ float dots[4][S_];
  int bid = blockIdx.x;             // 0..1023
  int tid = threadIdx.x;
  int lane = tid & 63, wv = tid >> 6;
  int m0 = bid * 4;

#pragma unroll
  for (int q = 0; q < 4; q++) {
    int idx = tid + q * 256;
    ((float4*)xs)[idx] = ((const float4*)(x + (size_t)m0 * C_))[idx];
  }
  __syncthreads();

#pragma unroll
  for (int q = 0; q < 2; q++) {
    int i8 = tid + q * 256;
    float4 a = ((const float4*)xs)[i8 * 2];
    float4 b = ((const float4*)xs)[i8 * 2 + 1];
    half8 v;
    v[0] = (_Float16)a.x; v[1] = (_Float16)a.y; v[2] = (_Float16)a.z; v[3] = (_Float16)a.w;
    v[4] = (_Float16)b.x; v[5] = (_Float16)b.y; v[6] = (_Float16)b.z; v[7] = (_Float16)b.w;
    ((half8*)(xh + (size_t)m0 * C_))[i8] = v;
  }

  const float* xrow = xs + wv * C_;
  for (int n = 0; n < 33; n++) {
    const float* wr = (n < 32) ? (w_wave + n * C_) : w_exp;
    float s = 0.f;
#pragma unroll
    for (int q = 0; q < 4; q++) {
      int k4 = lane + q * 64;
      float4 xv = ((const float4*)xrow)[k4];
      float4 wv4 = ((const float4*)wr)[k4];
      s += xv.x * wv4.x + xv.y * wv4.y + xv.z * wv4.z + xv.w * wv4.w;
    }
    for (int o = 32; o; o >>= 1) s += __shfl_xor(s, o);
    if (lane == 0) dots[wv][n] = s + ((n < 32) ? b_wave[n] : b_exp[0]);
  }
  __syncthreads();

  int m = m0 + wv;
  float v = (lane < 32) ? dots[wv][lane] : 0.f;
  float ss = v * v;
  for (int o = 32; o; o >>= 1) ss += __shfl_xor(ss, o);
  float scale = rsqrtf(ss * (1.f / 32.f) + 1e-6f);
  if (lane < 32) {
    float nv = dots[wv][lane] * scale * g_wave[lane];
    float sv = nv * sigmoidf_(nv);
    if (lane < 16) freq[m * H_ + lane] = sigmoidf_(sv) * 15.f + 1.f;
    else           phase[m * H_ + lane - 16] = tanhf(sv) * 16.f;
  }
  if (lane == 0) {
    float y = dots[wv][32];
    float nv = y * rsqrtf(y * y + 1e-6f) * g_exp[0];
    expn[m] = sigmoidf_(nv) * 3.5f + 0.5f;
  }
}

// ---------------------------------------------------------------------------
// FP16-MFMA GEMM, 128x128 tile, split-K=2, BK=32, 256 thr, DOUBLE-BUFFERED:
// stage(t+1) issued BEFORE compute(t); ONE __syncthreads per K-step, whose
// compiler vmcnt(0)-drain waits only the residual global latency (T3-min).
// LDS swizzle (rule #21): linear gload_lds dest + source seg' = seg^(row&3);
// ds_read applies the same involution. fp16 partials, no activation.
// ---------------------------------------------------------------------------
__global__ __launch_bounds__(256) void gemm_sk(
    const _Float16* __restrict__ A, const _Float16* __restrict__ Bw,
    _Float16* __restrict__ Cp, int M, int N, int Kd)
{
  __shared__ __align__(16) _Float16 As[2][128 * 32];   // 16 KB
  __shared__ __align__(16) _Float16 Bs[2][128 * 32];   // 16 KB
  int tid = threadIdx.x;
  int m0 = blockIdx.y * 128, n0 = blockIdx.x * 128;
  int z = blockIdx.z;
  int kbase = z * (Kd >> 1);
  int lane = tid & 63;
  int wid = tid >> 6, wm = wid >> 1, wn = wid & 1;

  f32x4 acc[4][4];
#pragma unroll
  for (int i = 0; i < 4; i++)
#pragma unroll
    for (int j = 0; j < 4; j++)
      acc[i][j] = (f32x4){0.f, 0.f, 0.f, 0.f};

  auto STAGE = [&](int buf, int k0) {
#pragma unroll
    for (int q = 0; q < 2; q++) {
      int idx = tid + q * 256;          // 0..511
      int row = idx >> 2, seg = idx & 3;
      int sseg = seg ^ (row & 3);
      const _Float16* ga = A  + (size_t)(m0 + row) * Kd + kbase + k0 + sseg * 8;
      const _Float16* gb = Bw + (size_t)(n0 + row) * Kd + kbase + k0 + sseg * 8;
      __builtin_amdgcn_global_load_lds(
          (const __attribute__((address_space(1))) unsigned int*)ga,
          (__attribute__((address_space(3))) unsigned int*)&As[buf][idx * 8], 16, 0, 0);
      __builtin_amdgcn_global_load_lds(
          (const __attribute__((address_space(1))) unsigned int*)gb,
          (__attribute__((address_space(3))) unsigned int*)&Bs[buf][idx * 8], 16, 0, 0);
    }
  };

  const int nt = (Kd >> 1) / 32;   // 16
  STAGE(0, 0);
  __syncthreads();                 // drain prologue stage
  int cur = 0;
  for (int t = 0; t < nt; t++) {
    if (t + 1 < nt) STAGE(cur ^ 1, (t + 1) * 32);   // prefetch next tile

    half8 aF[4], bF[4];
#pragma unroll
    for (int i = 0; i < 4; i++) {
      int ar = wm * 64 + i * 16 + (lane & 15);
      int ac = (lane >> 4) ^ (ar & 3);
      aF[i] = *(const half8*)&As[cur][ar * 32 + ac * 8];
    }
#pragma unroll
    for (int j = 0; j < 4; j++) {
      int br = wn * 64 + j * 16 + (lane & 15);
      int bc = (lane >> 4) ^ (br & 3);
      bF[j] = *(const half8*)&Bs[cur][br * 32 + bc * 8];
    }
#pragma unroll
    for (int i = 0; i < 4; i++)
#pragma unroll
      for (int j = 0; j < 4; j++)
        acc[i][j] = __builtin_amdgcn_mfma_f32_16x16x32_f16(aF[i], bF[j], acc[i][j], 0, 0, 0);

    __syncthreads();               // waits residual prefetch latency + LDS reuse
    cur ^= 1;
  }

  // C/D: col = lane&15, row = (lane>>4)*4 + reg
  _Float16* Cz = Cp + (size_t)z * M * N;
#pragma unroll
  for (int i = 0; i < 4; i++)
#pragma unroll
    for (int j = 0; j < 4; j++) {
      int col = n0 + wn * 64 + j * 16 + (lane & 15);
#pragma unroll
      for (int r = 0; r < 4; r++) {
        int row = m0 + wm * 64 + i * 16 + (lane >> 4) * 4 + r;
        Cz[(size_t)row * N + col] = (_Float16)acc[i][j][r];
      }
    }
}

// ---------------------------------------------------------------------------
// epi: out = silu(hp0 + hp1), fp32. 8 elems/thread.
// ---------------------------------------------------------------------------
__global__ __launch_bounds__(256) void epi(
    const _Float16* __restrict__ hp, float* __restrict__ out)
{
  int i = blockIdx.x * 256 + threadIdx.x;   // 0 .. 524287 (half8 units)
  half8 a = ((const half8*)hp)[i];
  half8 b = ((const half8*)(hp + (size_t)M_ * C_))[i];
  float o[8];
#pragma unroll
  for (int j = 0; j < 8; j++) {
    float t = (float)a[j] + (float)b[j];
    o[j] = t * sigmoidf_(t);
  }
  ((float4*)out)[i * 2]     = make_float4(o[0], o[1], o[2], o[3]);
  ((float4*)out)[i * 2 + 1] = make_float4(o[4], o[5], o[6], o[7]);
}

// ---------------------------------------------------------------------------
// Sampler: 256 thr/block, 2 tokens/block, XCD-swizzled.
//  A) sum split-K halves + bias -> rmsnorm+silu -> km in LDS
//  B) per-(h,s) kern/frac/fl (transcendentals once)
//  C) thread=(h,d8): half8 gathers; PACKED-FP16 lerp-accumulate
//     (v_pk_fma_f16, scalar splat), drained to f32 every 4 samples.
// ---------------------------------------------------------------------------
__global__ __launch_bounds__(256) void sampler(
    const _Float16* __restrict__ xh, const _Float16* __restrict__ ykp,
    const float* __restrict__ b_kern, const float* __restrict__ g_kern,
    const float* __restrict__ freq, const float* __restrict__ phase,
    const float* __restrict__ expn, _Float16* __restrict__ hidden)
{
  __shared__ float km[2][C_];        // 8 KB
  __shared__ float kw[2][H_][S_];
  __shared__ float fr[2][H_][S_];
  __shared__ int   fli[2][H_][S_];
  __shared__ float red2[2][2];
  int bid = blockIdx.x;                          // 0..2047
  int pair = ((bid & 7) << 8) + (bid >> 3);      // XCD swizzle (2048 = 8*256)
  int tid = threadIdx.x;
  int sub = tid >> 7, t = tid & 127;
  int m = pair * 2 + sub;
  int b = m >> 11, l = m & (L_ - 1);
  int lane = tid & 63;

  // A) split-K sum + bias + rmsnorm + silu -> km[sub][*]
  float yv[8];
  {
    half8 h0 = *(const half8*)(ykp + (size_t)m * C_ + t * 8);
    half8 h1 = *(const half8*)(ykp + (size_t)M_ * C_ + (size_t)m * C_ + t * 8);
    float ss = 0.f;
#pragma unroll
    for (int j = 0; j < 8; j++) {
      yv[j] = (float)h0[j] + (float)h1[j] + b_kern[t * 8 + j];
      ss += yv[j] * yv[j];
    }
    for (int o = 32; o; o >>= 1) ss += __shfl_xor(ss, o);
    if (lane == 0) red2[sub][t >> 6] = ss;
  }
  __syncthreads();
  {
    float scale = rsqrtf((red2[sub][0] + red2[sub][1]) * (1.f / 1024.f) + 1e-6f);
#pragma unroll
    for (int j = 0; j < 8; j++) {
      float nv = yv[j] * scale * g_kern[t * 8 + j];
      km[sub][t * 8 + j] = nv * sigmoidf_(nv);
    }
  }
  __syncthreads();

  // B) per-(h,s) sample params
  float e = expn[m];
  for (int i = t; i < H_ * S_; i += 128) {
    int h = i / S_, s = i - h * S_;
    float f  = freq[m * H_ + h];
    float ph = phase[m * H_ + h];
    float rel = (float)(s - 16) * f;
    float posv = (float)l + rel + ph;
    float kern = 0.f, frac = 0.f;
    int fl = 0;
    if (posv >= 0.f && posv < 2048.f) {
      float pc = fminf(posv, 2046.999f);
      fl = (int)pc;                      // pc>=0 -> trunc==floor, fl<=2046
      frac = pc - (float)fl;
      float ar = fabsf(rel);
      float idx_f = fminf(ar * (1.f / 256.f), 1.f) * 63.f;
      int i0 = (int)idx_f; if (i0 > 62) i0 = 62;
      float wc = idx_f - (float)i0;
      float k0 = km[sub][(h << 6) + i0];
      float k1 = km[sub][(h << 6) + i0 + 1];
      float powv = __expf(-e * __logf(1.f + ar * (1.f / 2048.f)));
      kern = (k0 * (1.f - wc) + k1 * wc) * powv;
    }
    kw[sub][h][s] = kern; fr[sub][h][s] = frac; fli[sub][h][s] = fl;
  }
  __syncthreads();

  // C) gather + packed-fp16 lerp + chunked f32 accumulate
  int h = t >> 3, d8 = (t & 7) << 3;
  const _Float16* xb = xh + (size_t)b * L_ * C_ + (h << 6) + d8;
  float accf[8] = {0.f, 0.f, 0.f, 0.f, 0.f, 0.f, 0.f, 0.f};
  half8 hzero;
#pragma unroll
  for (int j = 0; j < 8; j++) hzero[j] = (_Float16)0.f;
  half8 acch = hzero;
#pragma unroll
  for (int s = 0; s < S_; s++) {
    float kern = kw[sub][h][s];
    float frac = fr[sub][h][s];
    int fl = fli[sub][h][s];
    const _Float16* pf = xb + (size_t)fl * C_;
    half8 vf = *(const half8*)pf;
    half8 vc = *(const half8*)(pf + C_);
    _Float16 wfh = (_Float16)(kern * (1.f - frac));
    _Float16 wch = (_Float16)(kern * frac);
    acch = acch + vf * wfh + vc * wch;     // v_pk_fma_f16 x8
    if ((s & 3) == 3) {                    // drain every 4 samples
#pragma unroll
      for (int j = 0; j < 8; j++) accf[j] += (float)acch[j];
      acch = hzero;
    }
  }
#pragma unroll
  for (int j = 0; j < 8; j++) accf[j] += (float)acch[j];   // remainder (s=32)

  half8 o8;
#pragma unroll
  for (int j = 0; j < 8; j++) o8[j] = (_Float16)accf[j];
  *(half8*)(hidden + (size_t)m * C_ + (h << 6) + d8) = o8;
}

// ---------------------------------------------------------------------------
extern "C" void kernel_launch(void* const* d_in, const int* in_sizes, int n_in,
                              void* d_out, int out_size, void* d_ws, size_t ws_size,
                              hipStream_t stream) {
  const float* x      = (const float*)d_in[0];
  const float* w_wave = (const float*)d_in[1];
  const float* b_wave = (const float*)d_in[2];
  const float* g_wave = (const float*)d_in[3];
  const float* w_kern = (const float*)d_in[4];
  const float* b_kern = (const float*)d_in[5];
  const float* g_kern = (const float*)d_in[6];
  const float* w_exp  = (const float*)d_in[7];
  const float* b_exp  = (const float*)d_in[8];
  const float* g_exp  = (const float*)d_in[9];
  const float* w_out  = (const float*)d_in[10];
  float* out = (float*)d_out;

  char* ws = (char*)d_ws;
  _Float16* xhp    = (_Float16*)ws;                              //  0..8  MB
  _Float16* hidden = (_Float16*)(ws + (size_t) 8 * 1024 * 1024); //  8..16 MB
  _Float16* ykp    = (_Float16*)(ws + (size_t)16 * 1024 * 1024); // 16..32 MB (2 halves)
  _Float16* hp     = (_Float16*)(ws + (size_t)32 * 1024 * 1024); // 32..48 MB (2 halves)
  _Float16* wkh    = (_Float16*)(ws + (size_t)48 * 1024 * 1024); // 48..50 MB
  _Float16* woh    = (_Float16*)(ws + (size_t)50 * 1024 * 1024); // 50..52 MB
  float*    freqb  = (float*)(ws + (size_t)52 * 1024 * 1024);
  float*    phaseb = freqb + (size_t)M_ * H_;
  float*    expnb  = phaseb + (size_t)M_ * H_;

  conv_w<<<1024, 256, 0, stream>>>(w_kern, w_out, wkh, woh);
  prep<<<M_ / 4, 256, 0, stream>>>(x, w_wave, b_wave, g_wave, w_exp, b_exp, g_exp,
                                   xhp, freqb, phaseb, expnb);
  dim3 gg(C_ / 128, M_ / 128, 2);   // (8, 32, 2) = 512 blocks
  gemm_sk<<<gg, 256, 0, stream>>>(xhp, wkh, ykp, M_, C_, C_);
  sampler<<<M_ / 2, 256, 0, stream>>>(xhp, ykp, b_kern, g_kern,
                                      freqb, phaseb, expnb, hidden);
  gemm_sk<<<gg, 256, 0, stream>>>(hidden, woh, hp, M_, C_, C_);
  epi<<<(M_ * C_) / 2048, 256, 0, stream>>>(hp, out);
}

// Round 15
// 173.650 us; speedup vs baseline: 3.0619x; 1.0472x over previous
//
#include <hip/hip_runtime.h>
#include <hip/hip_bf16.h>
#include <math.h>

#define B_ 2
#define L_ 2048
#define C_ 1024
#define H_ 16
#define D_ 64
#define K_ 64
#define S_ 33
#define M_ (B_*L_)

typedef _Float16 half8 __attribute__((ext_vector_type(8)));
typedef _Float16 half4 __attribute__((ext_vector_type(4)));
typedef float f32x4 __attribute__((ext_vector_type(4)));

__device__ __forceinline__ float sigmoidf_(float v) { return 1.f / (1.f + __expf(-v)); }

// ---------------------------------------------------------------------------
// prep v2: 4 tokens/block (256 thr). Absorbs conv_w (weights->fp16).
// x rows register-resident (no LDS staging, no repeated LDS reads);
// dots split ACROSS waves (wave w does n = w, w+4, ...), each computing all
// 4 tokens -> each w_wave row read once per BLOCK (L2 traffic 540->135 MB).
// Dot accumulation order identical to v1 -> bit-identical freq/phase/expn.
// ---------------------------------------------------------------------------
__global__ __launch_bounds__(256) void prep(
    const float* __restrict__ x,
    const float* __restrict__ w_wave, const float* __restrict__ b_wave,
    const float* __restrict__ g_wave,
    const float* __restrict__ w_exp, const float* __restrict__ b_exp,
    const float* __restrict__ g_exp,
    const float* __restrict__ w_kern, const float* __restrict__ w_out,
    _Float16* __restrict__ wkh, _Float16* __restrict__ woh,
    _Float16* __restrict__ xh,
    float* __restrict__ freq, float* __restrict__ phase, float* __restrict__ expn)
{
  __shared__ float dots[4][S_];
  int bid = blockIdx.x;             // 0..1023
  int tid = threadIdx.x;
  int lane = tid & 63, wv = tid >> 6;
  int m0 = bid * 4;

  // --- absorbed conv_w: one half8 of weights per thread (262144 total) ---
  {
    int i = bid * 256 + tid;
    const float* src; _Float16* dst; int j;
    if (i < 131072) { src = w_kern; dst = wkh; j = i; }
    else            { src = w_out;  dst = woh; j = i - 131072; }
    float4 a = ((const float4*)src)[j * 2];
    float4 b = ((const float4*)src)[j * 2 + 1];
    half8 v;
    v[0] = (_Float16)a.x; v[1] = (_Float16)a.y; v[2] = (_Float16)a.z; v[3] = (_Float16)a.w;
    v[4] = (_Float16)b.x; v[5] = (_Float16)b.y; v[6] = (_Float16)b.z; v[7] = (_Float16)b.w;
    ((half8*)dst)[j] = v;
  }

  // --- load 4 token rows into registers (static indices only, rule #20) ---
  float4 xr[4][4];
#pragma unroll
  for (int t = 0; t < 4; t++)
#pragma unroll
    for (int q = 0; q < 4; q++)
      xr[t][q] = ((const float4*)(x + (size_t)(m0 + t) * C_))[lane + q * 64];

  // --- xh write: wave wv writes token m0+wv (re-load own row: L1 hit,
  //     avoids runtime-indexing xr by wv) ---
#pragma unroll
  for (int q = 0; q < 4; q++) {
    float4 a = ((const float4*)(x + (size_t)(m0 + wv) * C_))[lane + q * 64];
    half4 hv;
    hv[0] = (_Float16)a.x; hv[1] = (_Float16)a.y;
    hv[2] = (_Float16)a.z; hv[3] = (_Float16)a.w;
    ((half4*)(xh + (size_t)(m0 + wv) * C_))[lane + q * 64] = hv;
  }

  // --- dots: wave wv handles n = wv, wv+4, ... for ALL 4 tokens ---
  for (int n = wv; n < 33; n += 4) {
    const float* wr = (n < 32) ? (w_wave + n * C_) : w_exp;
    float s0 = 0.f, s1 = 0.f, s2 = 0.f, s3 = 0.f;
#pragma unroll
    for (int q = 0; q < 4; q++) {
      float4 w4 = ((const float4*)wr)[lane + q * 64];
      s0 += xr[0][q].x * w4.x + xr[0][q].y * w4.y + xr[0][q].z * w4.z + xr[0][q].w * w4.w;
      s1 += xr[1][q].x * w4.x + xr[1][q].y * w4.y + xr[1][q].z * w4.z + xr[1][q].w * w4.w;
      s2 += xr[2][q].x * w4.x + xr[2][q].y * w4.y + xr[2][q].z * w4.z + xr[2][q].w * w4.w;
      s3 += xr[3][q].x * w4.x + xr[3][q].y * w4.y + xr[3][q].z * w4.z + xr[3][q].w * w4.w;
    }
    for (int o = 32; o; o >>= 1) {
      s0 += __shfl_xor(s0, o); s1 += __shfl_xor(s1, o);
      s2 += __shfl_xor(s2, o); s3 += __shfl_xor(s3, o);
    }
    if (lane == 0) {
      float bb = (n < 32) ? b_wave[n] : b_exp[0];
      dots[0][n] = s0 + bb; dots[1][n] = s1 + bb;
      dots[2][n] = s2 + bb; dots[3][n] = s3 + bb;
    }
  }
  __syncthreads();

  // --- per-token transform (wave wv owns token m0+wv; same as v1) ---
  int m = m0 + wv;
  float v = (lane < 32) ? dots[wv][lane] : 0.f;
  float ss = v * v;
  for (int o = 32; o; o >>= 1) ss += __shfl_xor(ss, o);
  float scale = rsqrtf(ss * (1.f / 32.f) + 1e-6f);
  if (lane < 32) {
    float nv = dots[wv][lane] * scale * g_wave[lane];
    float sv = nv * sigmoidf_(nv);
    if (lane < 16) freq[m * H_ + lane] = sigmoidf_(sv) * 15.f + 1.f;
    else           phase[m * H_ + lane - 16] = tanhf(sv) * 16.f;
  }
  if (lane == 0) {
    float y = dots[wv][32];
    float nv = y * rsqrtf(y * y + 1e-6f) * g_exp[0];
    expn[m] = sigmoidf_(nv) * 3.5f + 0.5f;
  }
}

// ---------------------------------------------------------------------------
// FP16-MFMA GEMM, 128x128 tile, split-K=2, BK=32, 256 thr, DOUBLE-BUFFERED:
// stage(t+1) issued BEFORE compute(t); ONE __syncthreads per K-step.
// LDS swizzle (rule #21): linear gload_lds dest + source seg' = seg^(row&3);
// ds_read applies the same involution. fp16 partials, no activation.
// ---------------------------------------------------------------------------
__global__ __launch_bounds__(256) void gemm_sk(
    const _Float16* __restrict__ A, const _Float16* __restrict__ Bw,
    _Float16* __restrict__ Cp, int M, int N, int Kd)
{
  __shared__ __align__(16) _Float16 As[2][128 * 32];   // 16 KB
  __shared__ __align__(16) _Float16 Bs[2][128 * 32];   // 16 KB
  int tid = threadIdx.x;
  int m0 = blockIdx.y * 128, n0 = blockIdx.x * 128;
  int z = blockIdx.z;
  int kbase = z * (Kd >> 1);
  int lane = tid & 63;
  int wid = tid >> 6, wm = wid >> 1, wn = wid & 1;

  f32x4 acc[4][4];
#pragma unroll
  for (int i = 0; i < 4; i++)
#pragma unroll
    for (int j = 0; j < 4; j++)
      acc[i][j] = (f32x4){0.f, 0.f, 0.f, 0.f};

  auto STAGE = [&](int buf, int k0) {
#pragma unroll
    for (int q = 0; q < 2; q++) {
      int idx = tid + q * 256;          // 0..511
      int row = idx >> 2, seg = idx & 3;
      int sseg = seg ^ (row & 3);
      const _Float16* ga = A  + (size_t)(m0 + row) * Kd + kbase + k0 + sseg * 8;
      const _Float16* gb = Bw + (size_t)(n0 + row) * Kd + kbase + k0 + sseg * 8;
      __builtin_amdgcn_global_load_lds(
          (const __attribute__((address_space(1))) unsigned int*)ga,
          (__attribute__((address_space(3))) unsigned int*)&As[buf][idx * 8], 16, 0, 0);
      __builtin_amdgcn_global_load_lds(
          (const __attribute__((address_space(1))) unsigned int*)gb,
          (__attribute__((address_space(3))) unsigned int*)&Bs[buf][idx * 8], 16, 0, 0);
    }
  };

  const int nt = (Kd >> 1) / 32;   // 16
  STAGE(0, 0);
  __syncthreads();                 // drain prologue stage
  int cur = 0;
  for (int t = 0; t < nt; t++) {
    if (t + 1 < nt) STAGE(cur ^ 1, (t + 1) * 32);   // prefetch next tile

    half8 aF[4], bF[4];
#pragma unroll
    for (int i = 0; i < 4; i++) {
      int ar = wm * 64 + i * 16 + (lane & 15);
      int ac = (lane >> 4) ^ (ar & 3);
      aF[i] = *(const half8*)&As[cur][ar * 32 + ac * 8];
    }
#pragma unroll
    for (int j = 0; j < 4; j++) {
      int br = wn * 64 + j * 16 + (lane & 15);
      int bc = (lane >> 4) ^ (br & 3);
      bF[j] = *(const half8*)&Bs[cur][br * 32 + bc * 8];
    }
#pragma unroll
    for (int i = 0; i < 4; i++)
#pragma unroll
      for (int j = 0; j < 4; j++)
        acc[i][j] = __builtin_amdgcn_mfma_f32_16x16x32_f16(aF[i], bF[j], acc[i][j], 0, 0, 0);

    __syncthreads();               // waits residual prefetch latency + LDS reuse
    cur ^= 1;
  }

  // C/D: col = lane&15, row = (lane>>4)*4 + reg
  _Float16* Cz = Cp + (size_t)z * M * N;
#pragma unroll
  for (int i = 0; i < 4; i++)
#pragma unroll
    for (int j = 0; j < 4; j++) {
      int col = n0 + wn * 64 + j * 16 + (lane & 15);
#pragma unroll
      for (int r = 0; r < 4; r++) {
        int row = m0 + wm * 64 + i * 16 + (lane >> 4) * 4 + r;
        Cz[(size_t)row * N + col] = (_Float16)acc[i][j][r];
      }
    }
}

// ---------------------------------------------------------------------------
// epi: out = silu(hp0 + hp1), fp32. 8 elems/thread.
// ---------------------------------------------------------------------------
__global__ __launch_bounds__(256) void epi(
    const _Float16* __restrict__ hp, float* __restrict__ out)
{
  int i = blockIdx.x * 256 + threadIdx.x;   // 0 .. 524287 (half8 units)
  half8 a = ((const half8*)hp)[i];
  half8 b = ((const half8*)(hp + (size_t)M_ * C_))[i];
  float o[8];
#pragma unroll
  for (int j = 0; j < 8; j++) {
    float t = (float)a[j] + (float)b[j];
    o[j] = t * sigmoidf_(t);
  }
  ((float4*)out)[i * 2]     = make_float4(o[0], o[1], o[2], o[3]);
  ((float4*)out)[i * 2 + 1] = make_float4(o[4], o[5], o[6], o[7]);
}

// ---------------------------------------------------------------------------
// Sampler: 256 thr/block, 2 tokens/block, XCD-swizzled.
//  A) sum split-K halves + bias -> rmsnorm+silu -> km in LDS
//  B) per-(h,s) kern/frac/fl (transcendentals once)
//  C) thread=(h,d8): half8 gathers; PACKED-FP16 lerp-accumulate
//     (v_pk_fma_f16, scalar splat), drained to f32 every 4 samples.
// ---------------------------------------------------------------------------
__global__ __launch_bounds__(256) void sampler(
    const _Float16* __restrict__ xh, const _Float16* __restrict__ ykp,
    const float* __restrict__ b_kern, const float* __restrict__ g_kern,
    const float* __restrict__ freq, const float* __restrict__ phase,
    const float* __restrict__ expn, _Float16* __restrict__ hidden)
{
  __shared__ float km[2][C_];        // 8 KB
  __shared__ float kw[2][H_][S_];
  __shared__ float fr[2][H_][S_];
  __shared__ int   fli[2][H_][S_];
  __shared__ float red2[2][2];
  int bid = blockIdx.x;                          // 0..2047
  int pair = ((bid & 7) << 8) + (bid >> 3);      // XCD swizzle (2048 = 8*256)
  int tid = threadIdx.x;
  int sub = tid >> 7, t = tid & 127;
  int m = pair * 2 + sub;
  int b = m >> 11, l = m & (L_ - 1);
  int lane = tid & 63;

  // A) split-K sum + bias + rmsnorm + silu -> km[sub][*]
  float yv[8];
  {
    half8 h0 = *(const half8*)(ykp + (size_t)m * C_ + t * 8);
    half8 h1 = *(const half8*)(ykp + (size_t)M_ * C_ + (size_t)m * C_ + t * 8);
    float ss = 0.f;
#pragma unroll
    for (int j = 0; j < 8; j++) {
      yv[j] = (float)h0[j] + (float)h1[j] + b_kern[t * 8 + j];
      ss += yv[j] * yv[j];
    }
    for (int o = 32; o; o >>= 1) ss += __shfl_xor(ss, o);
    if (lane == 0) red2[sub][t >> 6] = ss;
  }
  __syncthreads();
  {
    float scale = rsqrtf((red2[sub][0] + red2[sub][1]) * (1.f / 1024.f) + 1e-6f);
#pragma unroll
    for (int j = 0; j < 8; j++) {
      float nv = yv[j] * scale * g_kern[t * 8 + j];
      km[sub][t * 8 + j] = nv * sigmoidf_(nv);
    }
  }
  __syncthreads();

  // B) per-(h,s) sample params
  float e = expn[m];
  for (int i = t; i < H_ * S_; i += 128) {
    int h = i / S_, s = i - h * S_;
    float f  = freq[m * H_ + h];
    float ph = phase[m * H_ + h];
    float rel = (float)(s - 16) * f;
    float posv = (float)l + rel + ph;
    float kern = 0.f, frac = 0.f;
    int fl = 0;
    if (posv >= 0.f && posv < 2048.f) {
      float pc = fminf(posv, 2046.999f);
      fl = (int)pc;                      // pc>=0 -> trunc==floor, fl<=2046
      frac = pc - (float)fl;
      float ar = fabsf(rel);
      float idx_f = fminf(ar * (1.f / 256.f), 1.f) * 63.f;
      int i0 = (int)idx_f; if (i0 > 62) i0 = 62;
      float wc = idx_f - (float)i0;
      float k0 = km[sub][(h << 6) + i0];
      float k1 = km[sub][(h << 6) + i0 + 1];
      float powv = __expf(-e * __logf(1.f + ar * (1.f / 2048.f)));
      kern = (k0 * (1.f - wc) + k1 * wc) * powv;
    }
    kw[sub][h][s] = kern; fr[sub][h][s] = frac; fli[sub][h][s] = fl;
  }
  __syncthreads();

  // C) gather + packed-fp16 lerp + chunked f32 accumulate
  int h = t >> 3, d8 = (t & 7) << 3;
  const _Float16* xb = xh + (size_t)b * L_ * C_ + (h << 6) + d8;
  float accf[8] = {0.f, 0.f, 0.f, 0.f, 0.f, 0.f, 0.f, 0.f};
  half8 hzero;
#pragma unroll
  for (int j = 0; j < 8; j++) hzero[j] = (_Float16)0.f;
  half8 acch = hzero;
#pragma unroll
  for (int s = 0; s < S_; s++) {
    float kern = kw[sub][h][s];
    float frac = fr[sub][h][s];
    int fl = fli[sub][h][s];
    const _Float16* pf = xb + (size_t)fl * C_;
    half8 vf = *(const half8*)pf;
    half8 vc = *(const half8*)(pf + C_);
    _Float16 wfh = (_Float16)(kern * (1.f - frac));
    _Float16 wch = (_Float16)(kern * frac);
    acch = acch + vf * wfh + vc * wch;     // v_pk_fma_f16 x8
    if ((s & 3) == 3) {                    // drain every 4 samples
#pragma unroll
      for (int j = 0; j < 8; j++) accf[j] += (float)acch[j];
      acch = hzero;
    }
  }
#pragma unroll
  for (int j = 0; j < 8; j++) accf[j] += (float)acch[j];   // remainder (s=32)

  half8 o8;
#pragma unroll
  for (int j = 0; j < 8; j++) o8[j] = (_Float16)accf[j];
  *(half8*)(hidden + (size_t)m * C_ + (h << 6) + d8) = o8;
}

// ---------------------------------------------------------------------------
extern "C" void kernel_launch(void* const* d_in, const int* in_sizes, int n_in,
                              void* d_out, int out_size, void* d_ws, size_t ws_size,
                              hipStream_t stream) {
  const float* x      = (const float*)d_in[0];
  const float* w_wave = (const float*)d_in[1];
  const float* b_wave = (const float*)d_in[2];
  const float* g_wave = (const float*)d_in[3];
  const float* w_kern = (const float*)d_in[4];
  const float* b_kern = (const float*)d_in[5];
  const float* g_kern = (const float*)d_in[6];
  const float* w_exp  = (const float*)d_in[7];
  const float* b_exp  = (const float*)d_in[8];
  const float* g_exp  = (const float*)d_in[9];
  const float* w_out  = (const float*)d_in[10];
  float* out = (float*)d_out;

  char* ws = (char*)d_ws;
  _Float16* xhp    = (_Float16*)ws;                              //  0..8  MB
  _Float16* hidden = (_Float16*)(ws + (size_t) 8 * 1024 * 1024); //  8..16 MB
  _Float16* ykp    = (_Float16*)(ws + (size_t)16 * 1024 * 1024); // 16..32 MB (2 halves)
  _Float16* hp     = (_Float16*)(ws + (size_t)32 * 1024 * 1024); // 32..48 MB (2 halves)
  _Float16* wkh    = (_Float16*)(ws + (size_t)48 * 1024 * 1024); // 48..50 MB
  _Float16* woh    = (_Float16*)(ws + (size_t)50 * 1024 * 1024); // 50..52 MB
  float*    freqb  = (float*)(ws + (size_t)52 * 1024 * 1024);
  float*    phaseb = freqb + (size_t)M_ * H_;
  float*    expnb  = phaseb + (size_t)M_ * H_;

  prep<<<M_ / 4, 256, 0, stream>>>(x, w_wave, b_wave, g_wave, w_exp, b_exp, g_exp,
                                   w_kern, w_out, wkh, woh,
                                   xhp, freqb, phaseb, expnb);
  dim3 gg(C_ / 128, M_ / 128, 2);   // (8, 32, 2) = 512 blocks
  gemm_sk<<<gg, 256, 0, stream>>>(xhp, wkh, ykp, M_, C_, C_);
  sampler<<<M_ / 2, 256, 0, stream>>>(xhp, ykp, b_kern, g_kern,
                                      freqb, phaseb, expnb, hidden);
  gemm_sk<<<gg, 256, 0, stream>>>(hidden, woh, hp, M_, C_, C_);
  epi<<<(M_ * C_) / 2048, 256, 0, stream>>>(hp, out);
}